// Round 4
// baseline (19355.345 us; speedup 1.0000x reference)
//
#include <hip/hip_runtime.h>

// ---------------- problem constants ----------------
static const long BATCH = 131072;
static const int NBLOCKS = 4096;   // 32 rows per block, 4096*32 == 131072

// ---------------- threefry2x32 (JAX-exact, key = (0, 42)) ----------------
__device__ __forceinline__ unsigned rotl32(unsigned x, int d) {
  return (x << d) | (x >> (32 - d));
}

struct U2 { unsigned a, b; };

__device__ __forceinline__ U2 threefry(unsigned x0, unsigned x1) {
  const unsigned ks0 = 0u, ks1 = 42u, ks2 = 0u ^ 42u ^ 0x1BD11BDAu;
  x0 += ks0; x1 += ks1;
#define TF_R4(A,B,C,D) \
  x0 += x1; x1 = rotl32(x1, A); x1 ^= x0; \
  x0 += x1; x1 = rotl32(x1, B); x1 ^= x0; \
  x0 += x1; x1 = rotl32(x1, C); x1 ^= x0; \
  x0 += x1; x1 = rotl32(x1, D); x1 ^= x0;
  TF_R4(13,15,26,6)  x0 += ks1; x1 += ks2 + 1u;
  TF_R4(17,29,16,24) x0 += ks2; x1 += ks0 + 2u;
  TF_R4(13,15,26,6)  x0 += ks0; x1 += ks1 + 3u;
  TF_R4(17,29,16,24) x0 += ks1; x1 += ks2 + 4u;
  TF_R4(13,15,26,6)  x0 += ks2; x1 += ks0 + 5u;
#undef TF_R4
  U2 r; r.a = x0; r.b = x1; return r;
}

// u[idx] of jax.random.uniform(key(42), (131072, 64), f32), idx row-major.
// JAX partitionable threefry (default since ~0.4.30), 32-bit draws:
//   counts1, counts2 = hi/lo 32-bit words of 64-bit index
//   bits1, bits2 = threefry2x32(key, (counts1, counts2))
//   bits32 = bits1 ^ bits2          <-- XOR of BOTH output words
__device__ __forceinline__ float jax_uniform(unsigned idx) {
  U2 r = threefry(0u, idx);          // idx < 2^23 so hi word is 0
  unsigned bits = r.a ^ r.b;         // partitionable 32-bit draw
  unsigned fb = (bits >> 9) | 0x3f800000u;
  return __uint_as_float(fb) - 1.0f;
}

// ---------------- fused-chain helpers (32 rows per block) ----------------
// GEMM: acc[r] = sum_k IN[r*M+k] * W[tid*M+k]   (thread 'tid' owns col tid)
template<int M, int N>
__device__ __forceinline__ void step_gemm(const double* IN, const float* __restrict__ W,
                                          int tid, double* acc) {
  if (tid < N) {
    #pragma unroll
    for (int r = 0; r < 32; ++r) acc[r] = 0.0;
    for (int k = 0; k < M; ++k) {
      double wv = (double)W[tid * M + k];
      #pragma unroll
      for (int r = 0; r < 32; ++r) acc[r] += IN[r * M + k] * wv;
    }
  }
}

// write h = acc + b into OUT (compact stride N)
template<int N>
__device__ __forceinline__ void step_write(double* OUT, const double* acc,
                                           const float* __restrict__ b, int tid) {
  if (tid < N) {
    double bj = (double)b[tid];
    #pragma unroll
    for (int r = 0; r < 32; ++r) OUT[r * N + tid] = acc[r] + bj;
  }
}

// per-block column stats of h = acc + b  ->  partials[blk*2N + {j, N+j}]
template<int N>
__device__ __forceinline__ void step_stats(const double* acc, const float* __restrict__ b,
                                           double* partials, int blk, int tid) {
  if (tid < N) {
    double bj = (double)b[tid], s = 0.0, q = 0.0;
    #pragma unroll
    for (int r = 0; r < 32; ++r) { double h = acc[r] + bj; s += h; q += h * h; }
    double* pp = partials + (long)blk * (2 * N);
    pp[tid] = s; pp[N + tid] = q;
  }
}

// in-place BN + ReLU on BUF[32][N]
template<int N>
__device__ __forceinline__ void apply_bn(double* BUF, const double* __restrict__ a,
                                         const double* __restrict__ c, int tid) {
  for (int idx = tid; idx < 32 * N; idx += 256) {
    int col = idx % N;
    double v = BUF[idx] * a[col] + c[col];
    BUF[idx] = v > 0.0 ? v : 0.0;
  }
}

// ---------------- the chain pass ----------------
// PL in 0..4: recompute chain up to h_PL, emit its per-block column stats.
// PL == 5:    full chain + final Linear + sigmoid + threefry sample + logsum.
template<int PL>
__global__ __launch_bounds__(256) void chain_pass(
    const float* __restrict__ ev,
    const float* __restrict__ W0, const float* __restrict__ b0,
    const float* __restrict__ W1, const float* __restrict__ b1,
    const float* __restrict__ W2, const float* __restrict__ b2,
    const float* __restrict__ W3, const float* __restrict__ b3,
    const float* __restrict__ W4, const float* __restrict__ b4,
    const float* __restrict__ W5, const float* __restrict__ b5,
    const double* __restrict__ bn_a, const double* __restrict__ bn_c,
    double* __restrict__ partials,
    float* __restrict__ out0, float* __restrict__ out1)
{
  __shared__ double SA[32 * 130];   // h0(130) / h2(90) / h4(50); also events f32 staging
  __shared__ double SB[32 * 110];   // h1(110) / h3(70); also log-prob tile [32][64]
  const int tid = threadIdx.x;
  const int blk = blockIdx.x;
  const long i0 = (long)blk * 32;
  double acc[32];

  // ---- layer 0: events (f32, chunk-staged in SA) -> h0 ----
  {
    float* evf = (float*)SA;        // float[32][256] per chunk
    if (tid < 130) {
      #pragma unroll
      for (int r = 0; r < 32; ++r) acc[r] = 0.0;
    }
    for (int c = 0; c < 4; ++c) {
      __syncthreads();              // previous chunk fully consumed
      for (int idx = tid; idx < 32 * 256; idx += 256) {
        int r = idx >> 8, kk = idx & 255;
        evf[idx] = ev[(i0 + r) * 1024 + c * 256 + kk];
      }
      __syncthreads();
      if (tid < 130) {
        for (int kk = 0; kk < 256; ++kk) {
          double wv = (double)W0[tid * 1024 + c * 256 + kk];
          #pragma unroll
          for (int r = 0; r < 32; ++r) acc[r] += (double)evf[r * 256 + kk] * wv;
        }
      }
    }
    __syncthreads();                // staging reads done before SA reuse
    if constexpr (PL == 0) { step_stats<130>(acc, b0, partials, blk, tid); return; }
    step_write<130>(SA, acc, b0, tid);
    __syncthreads();
    apply_bn<130>(SA, bn_a + 0, bn_c + 0, tid);
    __syncthreads();
  }
  if constexpr (PL >= 1) {
    step_gemm<130, 110>(SA, W1, tid, acc);
    if constexpr (PL == 1) { step_stats<110>(acc, b1, partials, blk, tid); return; }
    __syncthreads();
    step_write<110>(SB, acc, b1, tid);
    __syncthreads();
    apply_bn<110>(SB, bn_a + 130, bn_c + 130, tid);
    __syncthreads();
  }
  if constexpr (PL >= 2) {
    step_gemm<110, 90>(SB, W2, tid, acc);
    if constexpr (PL == 2) { step_stats<90>(acc, b2, partials, blk, tid); return; }
    __syncthreads();
    step_write<90>(SA, acc, b2, tid);
    __syncthreads();
    apply_bn<90>(SA, bn_a + 240, bn_c + 240, tid);
    __syncthreads();
  }
  if constexpr (PL >= 3) {
    step_gemm<90, 70>(SA, W3, tid, acc);
    if constexpr (PL == 3) { step_stats<70>(acc, b3, partials, blk, tid); return; }
    __syncthreads();
    step_write<70>(SB, acc, b3, tid);
    __syncthreads();
    apply_bn<70>(SB, bn_a + 330, bn_c + 330, tid);
    __syncthreads();
  }
  if constexpr (PL >= 4) {
    step_gemm<70, 50>(SB, W4, tid, acc);
    if constexpr (PL == 4) { step_stats<50>(acc, b4, partials, blk, tid); return; }
    __syncthreads();
    step_write<50>(SA, acc, b4, tid);
    __syncthreads();
    apply_bn<50>(SA, bn_a + 400, bn_c + 400, tid);
    __syncthreads();
  }
  if constexpr (PL == 5) {
    // final: h5 = act4 @ W5^T + b5 -> sigmoid -> sample -> log terms
    if (tid < 64) {
      #pragma unroll
      for (int r = 0; r < 32; ++r) acc[r] = 0.0;
      for (int k = 0; k < 50; ++k) {
        double wv = (double)W5[tid * 50 + k];
        #pragma unroll
        for (int r = 0; r < 32; ++r) acc[r] += SA[r * 50 + k] * wv;
      }
      double bj = (double)b5[tid];
      #pragma unroll
      for (int r = 0; r < 32; ++r) {
        double h = acc[r] + bj;
        double p = 1.0 / (1.0 + exp(-h));
        float uf = jax_uniform((unsigned)((i0 + r) * 64 + tid));
        bool ch = ((double)uf < 1.0 - p);     // chosen = 1 iff u < 1-p
        out0[(i0 + r) * 64 + tid] = ch ? 0.0f : 1.0f;  // mask = 1 - chosen
        double d = ch ? (1.0 - p) : p;        // |chosen - p|
        SB[r * 64 + tid] = log(d);
      }
    }
    __syncthreads();
    if (tid < 32) {
      double s = 0.0;
      for (int j = 0; j < 64; ++j) s += SB[tid * 64 + j];   // np's j-order
      out1[i0 + tid] = (float)s;
    }
  }
}

// ---------------- BN stats finalize: partials -> a, c ----------------
template<int N>
__global__ __launch_bounds__(256) void bn_finalize2(
    const double* __restrict__ partials, int nblocks,
    const float* __restrict__ g, const float* __restrict__ be,
    double* __restrict__ a, double* __restrict__ c)
{
  const int j = blockIdx.x;
  const int tid = threadIdx.x;
  double s = 0.0, q = 0.0;
  for (int b = tid; b < nblocks; b += 256) {
    const double* p = partials + (long)b * (2 * N);
    s += p[j];
    q += p[N + j];
  }
  __shared__ double ls[256], lq[256];
  ls[tid] = s; lq[tid] = q;
  __syncthreads();
  for (int off = 128; off > 0; off >>= 1) {
    if (tid < off) { ls[tid] += ls[tid + off]; lq[tid] += lq[tid + off]; }
    __syncthreads();
  }
  if (tid == 0) {
    double mu  = ls[0] * (1.0 / 131072.0);   // exact: * 2^-17
    double var = lq[0] * (1.0 / 131072.0) - mu * mu;
    double aj  = (double)g[j] / sqrt(var + 1e-5);
    a[j] = aj;
    c[j] = (double)be[j] - mu * aj;
  }
}

// ---------------- host side ----------------
extern "C" void kernel_launch(void* const* d_in, const int* in_sizes, int n_in,
                              void* d_out, int out_size, void* d_ws, size_t ws_size,
                              hipStream_t stream)
{
  const float* F[23];
  for (int i = 0; i < 23; ++i) F[i] = (const float*)d_in[i];
  const float* ev = F[0];
  float* out0 = (float*)d_out;
  float* out1 = out0 + BATCH * 64;

  // partials live in d_out's first 8.5 MB (fully overwritten by the final pass
  // AFTER their last consumption). BN params (7.2 KB) live in ws.
  double* partials = (double*)d_out;                 // 4096 * 260 doubles max
  double* bn_a = (double*)d_ws;                      // 450 doubles
  double* bn_c = bn_a + 450;                         // 450 doubles

  dim3 g(NBLOCKS), b(256);
#define ARGS ev, F[1],F[2], F[5],F[6], F[9],F[10], F[13],F[14], F[17],F[18], \
             F[21],F[22], bn_a, bn_c, partials, out0, out1
  chain_pass<0><<<g, b, 0, stream>>>(ARGS);
  bn_finalize2<130><<<dim3(130), b, 0, stream>>>(partials, NBLOCKS, F[3],  F[4],  bn_a + 0,   bn_c + 0);
  chain_pass<1><<<g, b, 0, stream>>>(ARGS);
  bn_finalize2<110><<<dim3(110), b, 0, stream>>>(partials, NBLOCKS, F[7],  F[8],  bn_a + 130, bn_c + 130);
  chain_pass<2><<<g, b, 0, stream>>>(ARGS);
  bn_finalize2<90><<<dim3(90),  b, 0, stream>>>(partials, NBLOCKS, F[11], F[12], bn_a + 240, bn_c + 240);
  chain_pass<3><<<g, b, 0, stream>>>(ARGS);
  bn_finalize2<70><<<dim3(70),  b, 0, stream>>>(partials, NBLOCKS, F[15], F[16], bn_a + 330, bn_c + 330);
  chain_pass<4><<<g, b, 0, stream>>>(ARGS);
  bn_finalize2<50><<<dim3(50),  b, 0, stream>>>(partials, NBLOCKS, F[19], F[20], bn_a + 400, bn_c + 400);
  chain_pass<5><<<g, b, 0, stream>>>(ARGS);
#undef ARGS
}

// Round 5
// 6177.368 us; speedup vs baseline: 3.1333x; 3.1333x over previous
//
#include <hip/hip_runtime.h>

// ---------------- problem constants ----------------
static const long BATCH = 131072;
static const int ROWS = 32;                  // rows per block
static const int NBLOCKS = 4096;             // 4096*32 == 131072

// ---------------- threefry2x32 (JAX partitionable, key = (0, 42)) ----------
__device__ __forceinline__ unsigned rotl32(unsigned x, int d) {
  return (x << d) | (x >> (32 - d));
}

struct U2 { unsigned a, b; };

__device__ __forceinline__ U2 threefry(unsigned x0, unsigned x1) {
  const unsigned ks0 = 0u, ks1 = 42u, ks2 = 0u ^ 42u ^ 0x1BD11BDAu;
  x0 += ks0; x1 += ks1;
#define TF_R4(A,B,C,D) \
  x0 += x1; x1 = rotl32(x1, A); x1 ^= x0; \
  x0 += x1; x1 = rotl32(x1, B); x1 ^= x0; \
  x0 += x1; x1 = rotl32(x1, C); x1 ^= x0; \
  x0 += x1; x1 = rotl32(x1, D); x1 ^= x0;
  TF_R4(13,15,26,6)  x0 += ks1; x1 += ks2 + 1u;
  TF_R4(17,29,16,24) x0 += ks2; x1 += ks0 + 2u;
  TF_R4(13,15,26,6)  x0 += ks0; x1 += ks1 + 3u;
  TF_R4(17,29,16,24) x0 += ks1; x1 += ks2 + 4u;
  TF_R4(13,15,26,6)  x0 += ks2; x1 += ks0 + 5u;
#undef TF_R4
  U2 r; r.a = x0; r.b = x1; return r;
}

// partitionable 32-bit draw: bits1 ^ bits2  (VERIFIED passing in round 4)
__device__ __forceinline__ float jax_uniform(unsigned idx) {
  U2 r = threefry(0u, idx);
  unsigned bits = r.a ^ r.b;
  unsigned fb = (bits >> 9) | 0x3f800000u;
  return __uint_as_float(fb) - 1.0f;
}

// ======================= FAST PATH: stored-h =======================
// out h[B][N] = act(in[B][M]) @ W[N][M]^T + b, h stored f64; per-block col
// sum/sumsq partials. MODE 0: in = raw f32 events. MODE 1: in = f64 h_prev,
// act = relu(in*bna + bnc).
template<int M, int N, int MODE>
__global__ __launch_bounds__(256) void gemm_store(
    const void* __restrict__ inv, const float* __restrict__ W,
    const float* __restrict__ bias,
    const double* __restrict__ bna, const double* __restrict__ bnc,
    double* __restrict__ hout, double* __restrict__ partials)
{
  constexpr int BK = 32;
  constexpr int NC = (N + 63) / 64;
  __shared__ double INS[ROWS][BK + 2];     // input tile (post-act), row-major
  __shared__ double WS[BK][N + 1];         // W chunk, [kk][j]
  __shared__ double SSs[4][N], SSq[4][N];  // per-rowgroup col stats

  const int tid = threadIdx.x;
  const int c = tid & 63, g = tid >> 6;
  const long i0 = (long)blockIdx.x * ROWS;

  int jj[NC]; bool act[NC];
  #pragma unroll
  for (int m = 0; m < NC; ++m) {
    int j = c + 64 * m;
    act[m] = (j < N);
    jj[m] = act[m] ? j : 0;
  }

  double acc[8][NC];
  #pragma unroll
  for (int rr = 0; rr < 8; ++rr)
    #pragma unroll
    for (int m = 0; m < NC; ++m) acc[rr][m] = 0.0;

  for (int k0 = 0; k0 < M; k0 += BK) {
    // ---- stage input tile (with act) ----
    for (int idx = tid; idx < ROWS * BK; idx += 256) {
      int r = idx >> 5, ii = idx & 31;
      int k = k0 + ii;
      double v = 0.0;
      if (k < M) {
        if constexpr (MODE == 0) {
          v = (double)((const float*)inv)[(i0 + r) * (long)M + k];
        } else {
          v = ((const double*)inv)[(i0 + r) * (long)M + k];
          v = v * bna[k] + bnc[k];
          v = v > 0.0 ? v : 0.0;
        }
      }
      INS[r][ii] = v;
    }
    // ---- stage W chunk (f32 -> f64) ----
    for (int idx = tid; idx < N * BK; idx += 256) {
      int j = idx >> 5, ii = idx & 31;
      int k = k0 + ii;
      WS[ii][j] = (k < M) ? (double)W[(long)j * M + k] : 0.0;
    }
    __syncthreads();
    // ---- inner: k unrolled x2, b128 broadcast input reads ----
    #pragma unroll
    for (int kk = 0; kk < BK; kk += 2) {
      double2 av[8];
      #pragma unroll
      for (int rr = 0; rr < 8; ++rr)
        av[rr] = *(const double2*)&INS[g * 8 + rr][kk];
      #pragma unroll
      for (int m = 0; m < NC; ++m) {
        double w0 = WS[kk][jj[m]], w1 = WS[kk + 1][jj[m]];
        #pragma unroll
        for (int rr = 0; rr < 8; ++rr)
          acc[rr][m] += av[rr].x * w0 + av[rr].y * w1;
      }
    }
    __syncthreads();
  }

  // ---- epilogue: bias, store h, per-block column stats ----
  #pragma unroll
  for (int m = 0; m < NC; ++m) {
    if (act[m]) {
      double bj = (double)bias[jj[m]];
      double s = 0.0, q = 0.0;
      #pragma unroll
      for (int rr = 0; rr < 8; ++rr) {
        double h = acc[rr][m] + bj;
        hout[(i0 + g * 8 + rr) * (long)N + jj[m]] = h;
        s += h; q += h * h;
      }
      SSs[g][jj[m]] = s; SSq[g][jj[m]] = q;
    }
  }
  __syncthreads();
  double* pp = partials + (long)blockIdx.x * (2 * N);
  for (int j = tid; j < N; j += 256) {
    pp[j]     = SSs[0][j] + SSs[1][j] + SSs[2][j] + SSs[3][j];
    pp[N + j] = SSq[0][j] + SSq[1][j] + SSq[2][j] + SSq[3][j];
  }
}

// final: BN+ReLU(h4) -> Linear(50->64) -> sigmoid -> sample -> logsum
__global__ __launch_bounds__(256) void final_store(
    const double* __restrict__ h4,
    const double* __restrict__ bna, const double* __restrict__ bnc,
    const float* __restrict__ W5, const float* __restrict__ b5,
    float* __restrict__ out0, float* __restrict__ out1)
{
  __shared__ double A5[ROWS][51];   // BN'd act4
  __shared__ double W5S[50][65];    // [k][j]
  __shared__ double T[ROWS][65];    // log terms
  const int tid = threadIdx.x;
  const int c = tid & 63, g = tid >> 6;
  const long i0 = (long)blockIdx.x * ROWS;

  for (int idx = tid; idx < ROWS * 50; idx += 256) {
    int r = idx / 50, k = idx % 50;
    double v = h4[(i0 + r) * 50 + k] * bna[k] + bnc[k];
    A5[r][k] = v > 0.0 ? v : 0.0;
  }
  for (int idx = tid; idx < 64 * 50; idx += 256) {
    int j = idx / 50, k = idx % 50;
    W5S[k][j] = (double)W5[j * 50 + k];
  }
  __syncthreads();

  double acc[8];
  #pragma unroll
  for (int rr = 0; rr < 8; ++rr) acc[rr] = 0.0;
  for (int k = 0; k < 50; ++k) {
    double w = W5S[k][c];
    #pragma unroll
    for (int rr = 0; rr < 8; ++rr) acc[rr] += A5[g * 8 + rr][k] * w;
  }
  double bj = (double)b5[c];
  #pragma unroll
  for (int rr = 0; rr < 8; ++rr) {
    int r = g * 8 + rr;
    double h = acc[rr] + bj;
    double p = 1.0 / (1.0 + exp(-h));
    float uf = jax_uniform((unsigned)((i0 + r) * 64 + c));
    bool ch = ((double)uf < 1.0 - p);
    out0[(i0 + r) * 64 + c] = ch ? 0.0f : 1.0f;
    T[r][c] = log(ch ? (1.0 - p) : p);
  }
  __syncthreads();
  for (int r = tid; r < ROWS; r += 256) {
    double s = 0.0;
    for (int j = 0; j < 64; ++j) s += T[r][j];
    out1[i0 + r] = (float)s;
  }
}

// ======================= FALLBACK: recompute chain (verified) ==============
template<int M, int N>
__device__ __forceinline__ void step_gemm(const double* IN, const float* __restrict__ W,
                                          int tid, double* acc) {
  if (tid < N) {
    #pragma unroll
    for (int r = 0; r < 32; ++r) acc[r] = 0.0;
    for (int k = 0; k < M; ++k) {
      double wv = (double)W[tid * M + k];
      #pragma unroll
      for (int r = 0; r < 32; ++r) acc[r] += IN[r * M + k] * wv;
    }
  }
}

template<int N>
__device__ __forceinline__ void step_write(double* OUT, const double* acc,
                                           const float* __restrict__ b, int tid) {
  if (tid < N) {
    double bj = (double)b[tid];
    #pragma unroll
    for (int r = 0; r < 32; ++r) OUT[r * N + tid] = acc[r] + bj;
  }
}

template<int N>
__device__ __forceinline__ void step_stats(const double* acc, const float* __restrict__ b,
                                           double* partials, int blk, int tid) {
  if (tid < N) {
    double bj = (double)b[tid], s = 0.0, q = 0.0;
    #pragma unroll
    for (int r = 0; r < 32; ++r) { double h = acc[r] + bj; s += h; q += h * h; }
    double* pp = partials + (long)blk * (2 * N);
    pp[tid] = s; pp[N + tid] = q;
  }
}

template<int N>
__device__ __forceinline__ void apply_bn(double* BUF, const double* __restrict__ a,
                                         const double* __restrict__ c, int tid) {
  for (int idx = tid; idx < 32 * N; idx += 256) {
    int col = idx % N;
    double v = BUF[idx] * a[col] + c[col];
    BUF[idx] = v > 0.0 ? v : 0.0;
  }
}

template<int PL>
__global__ __launch_bounds__(256) void chain_pass(
    const float* __restrict__ ev,
    const float* __restrict__ W0, const float* __restrict__ b0,
    const float* __restrict__ W1, const float* __restrict__ b1,
    const float* __restrict__ W2, const float* __restrict__ b2,
    const float* __restrict__ W3, const float* __restrict__ b3,
    const float* __restrict__ W4, const float* __restrict__ b4,
    const float* __restrict__ W5, const float* __restrict__ b5,
    const double* __restrict__ bn_a, const double* __restrict__ bn_c,
    double* __restrict__ partials,
    float* __restrict__ out0, float* __restrict__ out1)
{
  __shared__ double SA[32 * 130];
  __shared__ double SB[32 * 110];
  const int tid = threadIdx.x;
  const int blk = blockIdx.x;
  const long i0 = (long)blk * 32;
  double acc[32];

  {
    float* evf = (float*)SA;
    if (tid < 130) {
      #pragma unroll
      for (int r = 0; r < 32; ++r) acc[r] = 0.0;
    }
    for (int c = 0; c < 4; ++c) {
      __syncthreads();
      for (int idx = tid; idx < 32 * 256; idx += 256) {
        int r = idx >> 8, kk = idx & 255;
        evf[idx] = ev[(i0 + r) * 1024 + c * 256 + kk];
      }
      __syncthreads();
      if (tid < 130) {
        for (int kk = 0; kk < 256; ++kk) {
          double wv = (double)W0[tid * 1024 + c * 256 + kk];
          #pragma unroll
          for (int r = 0; r < 32; ++r) acc[r] += (double)evf[r * 256 + kk] * wv;
        }
      }
    }
    __syncthreads();
    if constexpr (PL == 0) { step_stats<130>(acc, b0, partials, blk, tid); return; }
    step_write<130>(SA, acc, b0, tid);
    __syncthreads();
    apply_bn<130>(SA, bn_a + 0, bn_c + 0, tid);
    __syncthreads();
  }
  if constexpr (PL >= 1) {
    step_gemm<130, 110>(SA, W1, tid, acc);
    if constexpr (PL == 1) { step_stats<110>(acc, b1, partials, blk, tid); return; }
    __syncthreads();
    step_write<110>(SB, acc, b1, tid);
    __syncthreads();
    apply_bn<110>(SB, bn_a + 130, bn_c + 130, tid);
    __syncthreads();
  }
  if constexpr (PL >= 2) {
    step_gemm<110, 90>(SB, W2, tid, acc);
    if constexpr (PL == 2) { step_stats<90>(acc, b2, partials, blk, tid); return; }
    __syncthreads();
    step_write<90>(SA, acc, b2, tid);
    __syncthreads();
    apply_bn<90>(SA, bn_a + 240, bn_c + 240, tid);
    __syncthreads();
  }
  if constexpr (PL >= 3) {
    step_gemm<90, 70>(SA, W3, tid, acc);
    if constexpr (PL == 3) { step_stats<70>(acc, b3, partials, blk, tid); return; }
    __syncthreads();
    step_write<70>(SB, acc, b3, tid);
    __syncthreads();
    apply_bn<70>(SB, bn_a + 330, bn_c + 330, tid);
    __syncthreads();
  }
  if constexpr (PL >= 4) {
    step_gemm<70, 50>(SB, W4, tid, acc);
    if constexpr (PL == 4) { step_stats<50>(acc, b4, partials, blk, tid); return; }
    __syncthreads();
    step_write<50>(SA, acc, b4, tid);
    __syncthreads();
    apply_bn<50>(SA, bn_a + 400, bn_c + 400, tid);
    __syncthreads();
  }
  if constexpr (PL == 5) {
    if (tid < 64) {
      #pragma unroll
      for (int r = 0; r < 32; ++r) acc[r] = 0.0;
      for (int k = 0; k < 50; ++k) {
        double wv = (double)W5[tid * 50 + k];
        #pragma unroll
        for (int r = 0; r < 32; ++r) acc[r] += SA[r * 50 + k] * wv;
      }
      double bj = (double)b5[tid];
      #pragma unroll
      for (int r = 0; r < 32; ++r) {
        double h = acc[r] + bj;
        double p = 1.0 / (1.0 + exp(-h));
        float uf = jax_uniform((unsigned)((i0 + r) * 64 + tid));
        bool ch = ((double)uf < 1.0 - p);
        out0[(i0 + r) * 64 + tid] = ch ? 0.0f : 1.0f;
        double d = ch ? (1.0 - p) : p;
        SB[r * 64 + tid] = log(d);
      }
    }
    __syncthreads();
    if (tid < 32) {
      double s = 0.0;
      for (int j = 0; j < 64; ++j) s += SB[tid * 64 + j];
      out1[i0 + tid] = (float)s;
    }
  }
}

// ---------------- BN stats finalize: partials -> a, c ----------------
template<int N>
__global__ __launch_bounds__(256) void bn_finalize2(
    const double* __restrict__ partials, int nblocks,
    const float* __restrict__ g, const float* __restrict__ be,
    double* __restrict__ a, double* __restrict__ c)
{
  const int j = blockIdx.x;
  const int tid = threadIdx.x;
  double s = 0.0, q = 0.0;
  for (int b = tid; b < nblocks; b += 256) {
    const double* p = partials + (long)b * (2 * N);
    s += p[j];
    q += p[N + j];
  }
  __shared__ double ls[256], lq[256];
  ls[tid] = s; lq[tid] = q;
  __syncthreads();
  for (int off = 128; off > 0; off >>= 1) {
    if (tid < off) { ls[tid] += ls[tid + off]; lq[tid] += lq[tid + off]; }
    __syncthreads();
  }
  if (tid == 0) {
    double mu  = ls[0] * (1.0 / 131072.0);
    double var = lq[0] * (1.0 / 131072.0) - mu * mu;
    double aj  = (double)g[j] / sqrt(var + 1e-5);
    a[j] = aj;
    c[j] = (double)be[j] - mu * aj;
  }
}

// ---------------- host side ----------------
extern "C" void kernel_launch(void* const* d_in, const int* in_sizes, int n_in,
                              void* d_out, int out_size, void* d_ws, size_t ws_size,
                              hipStream_t stream)
{
  const float* F[23];
  for (int i = 0; i < 23; ++i) F[i] = (const float*)d_in[i];
  const float* ev = F[0];
  float* out0 = (float*)d_out;
  float* out1 = out0 + BATCH * 64;

  // partials live in d_out (8.5 MB, consumed before final pass writes out).
  double* partials = (double*)d_out;
  double* bn_a = (double*)d_ws;       // 450 doubles
  double* bn_c = bn_a + 450;          // 450 doubles

  char* ws = (char*)d_ws;
  size_t used = (size_t)((char*)(bn_c + 450) - ws);
  used = (used + 255) & ~(size_t)255;
  const size_t needA = (size_t)BATCH * 130 * 8;   // 136.3 MB
  const size_t needB = (size_t)BATCH * 110 * 8;   // 115.3 MB

  dim3 g(NBLOCKS), b(256);

  if (ws_size >= used + needA + needB) {
    // ---------- fast stored-h path ----------
    double* bufA = (double*)(ws + used);
    double* bufB = (double*)(ws + used + needA);
    gemm_store<1024, 130, 0><<<g, b, 0, stream>>>(ev, F[1], F[2],
        nullptr, nullptr, bufA, partials);
    bn_finalize2<130><<<dim3(130), b, 0, stream>>>(partials, NBLOCKS, F[3], F[4], bn_a + 0, bn_c + 0);
    gemm_store<130, 110, 1><<<g, b, 0, stream>>>(bufA, F[5], F[6],
        bn_a + 0, bn_c + 0, bufB, partials);
    bn_finalize2<110><<<dim3(110), b, 0, stream>>>(partials, NBLOCKS, F[7], F[8], bn_a + 130, bn_c + 130);
    gemm_store<110, 90, 1><<<g, b, 0, stream>>>(bufB, F[9], F[10],
        bn_a + 130, bn_c + 130, bufA, partials);
    bn_finalize2<90><<<dim3(90), b, 0, stream>>>(partials, NBLOCKS, F[11], F[12], bn_a + 240, bn_c + 240);
    gemm_store<90, 70, 1><<<g, b, 0, stream>>>(bufA, F[13], F[14],
        bn_a + 240, bn_c + 240, bufB, partials);
    bn_finalize2<70><<<dim3(70), b, 0, stream>>>(partials, NBLOCKS, F[15], F[16], bn_a + 330, bn_c + 330);
    gemm_store<70, 50, 1><<<g, b, 0, stream>>>(bufB, F[17], F[18],
        bn_a + 330, bn_c + 330, bufA, partials);
    bn_finalize2<50><<<dim3(50), b, 0, stream>>>(partials, NBLOCKS, F[19], F[20], bn_a + 400, bn_c + 400);
    final_store<<<g, b, 0, stream>>>(bufA, bn_a + 400, bn_c + 400, F[21], F[22], out0, out1);
  } else {
    // ---------- fallback: verified recompute chain ----------
#define ARGS ev, F[1],F[2], F[5],F[6], F[9],F[10], F[13],F[14], F[17],F[18], \
             F[21],F[22], bn_a, bn_c, partials, out0, out1
    chain_pass<0><<<g, b, 0, stream>>>(ARGS);
    bn_finalize2<130><<<dim3(130), b, 0, stream>>>(partials, NBLOCKS, F[3],  F[4],  bn_a + 0,   bn_c + 0);
    chain_pass<1><<<g, b, 0, stream>>>(ARGS);
    bn_finalize2<110><<<dim3(110), b, 0, stream>>>(partials, NBLOCKS, F[7],  F[8],  bn_a + 130, bn_c + 130);
    chain_pass<2><<<g, b, 0, stream>>>(ARGS);
    bn_finalize2<90><<<dim3(90),  b, 0, stream>>>(partials, NBLOCKS, F[11], F[12], bn_a + 240, bn_c + 240);
    chain_pass<3><<<g, b, 0, stream>>>(ARGS);
    bn_finalize2<70><<<dim3(70),  b, 0, stream>>>(partials, NBLOCKS, F[15], F[16], bn_a + 330, bn_c + 330);
    chain_pass<4><<<g, b, 0, stream>>>(ARGS);
    bn_finalize2<50><<<dim3(50),  b, 0, stream>>>(partials, NBLOCKS, F[19], F[20], bn_a + 400, bn_c + 400);
    chain_pass<5><<<g, b, 0, stream>>>(ARGS);
#undef ARGS
  }
}

// Round 7
// 1556.631 us; speedup vs baseline: 12.4341x; 3.9684x over previous
//
#include <hip/hip_runtime.h>

// ---------------- problem constants ----------------
static const long BATCH = 131072;
static const int ROWS = 32;                  // rows per block (final/fallback)
static const int NBLOCKS = 4096;             // fallback/final grid
static const int GBLOCKS = 2048;             // gemm_mfma grid (64 rows each)

using f64x4 = __attribute__((ext_vector_type(4))) double;

// ---------------- threefry2x32 (JAX partitionable, key = (0, 42)) ----------
__device__ __forceinline__ unsigned rotl32(unsigned x, int d) {
  return (x << d) | (x >> (32 - d));
}

struct U2 { unsigned a, b; };

__device__ __forceinline__ U2 threefry(unsigned x0, unsigned x1) {
  const unsigned ks0 = 0u, ks1 = 42u, ks2 = 0u ^ 42u ^ 0x1BD11BDAu;
  x0 += ks0; x1 += ks1;
#define TF_R4(A,B,C,D) \
  x0 += x1; x1 = rotl32(x1, A); x1 ^= x0; \
  x0 += x1; x1 = rotl32(x1, B); x1 ^= x0; \
  x0 += x1; x1 = rotl32(x1, C); x1 ^= x0; \
  x0 += x1; x1 = rotl32(x1, D); x1 ^= x0;
  TF_R4(13,15,26,6)  x0 += ks1; x1 += ks2 + 1u;
  TF_R4(17,29,16,24) x0 += ks2; x1 += ks0 + 2u;
  TF_R4(13,15,26,6)  x0 += ks0; x1 += ks1 + 3u;
  TF_R4(17,29,16,24) x0 += ks1; x1 += ks2 + 4u;
  TF_R4(13,15,26,6)  x0 += ks2; x1 += ks0 + 5u;
#undef TF_R4
  U2 r; r.a = x0; r.b = x1; return r;
}

// partitionable 32-bit draw: bits1 ^ bits2  (VERIFIED passing, round 4)
__device__ __forceinline__ float jax_uniform(unsigned idx) {
  U2 r = threefry(0u, idx);
  unsigned bits = r.a ^ r.b;
  unsigned fb = (bits >> 9) | 0x3f800000u;
  return __uint_as_float(fb) - 1.0f;
}

// ============ f64-MFMA D-fragment layout probe (runs on device) ============
// Feeds v_mfma_f64_16x16x4 through the EXACT staging/read pattern the main
// GEMM uses, with calibrated inputs so acc[r] reveals the true (row,col) of
// each (lane,reg) D element. maps[l] packs 4 bytes: ((row<<4)|col) per reg.
__global__ __launch_bounds__(64) void probe_layout(unsigned* __restrict__ maps) {
  __shared__ double X1[16][5], X2[16][5], W1s[4][17], W2s[4][17];
  const int l = threadIdx.x;
  const int lr = l & 15, lk = l >> 4;
  // stage: X[i][k], Ws[k][j] = W[j][k]  (64 elements each, one per thread)
  {
    int i = l >> 2, k = l & 3;
    X1[i][k] = (k == 0) ? (double)i : 0.0;   // D1[i][j] = i
    X2[i][k] = (k == 0) ? 1.0 : 0.0;         // D2[i][j] = j
    W1s[k][i] = (k == 0) ? 1.0 : 0.0;
    W2s[k][i] = (k == 0) ? (double)i : 0.0;
  }
  __syncthreads();
  f64x4 a1 = {0.0, 0.0, 0.0, 0.0}, a2 = {0.0, 0.0, 0.0, 0.0};
  // identical read pattern to gemm_mfma: aA = XS[row=lr][k=lk], bB = WS[k=lk][j=lr]
  a1 = __builtin_amdgcn_mfma_f64_16x16x4f64(X1[lr][lk], W1s[lk][lr], a1, 0, 0, 0);
  a2 = __builtin_amdgcn_mfma_f64_16x16x4f64(X2[lr][lk], W2s[lk][lr], a2, 0, 0, 0);
  unsigned m = 0;
  #pragma unroll
  for (int r = 0; r < 4; ++r) {
    int row = (int)(a1[r] + 0.5);
    int col = (int)(a2[r] + 0.5);
    m |= (unsigned)(((row & 15) << 4) | (col & 15)) << (8 * r);
  }
  maps[l] = m;
}

// ======================= FAST PATH: f64-MFMA GEMM =======================
// h[B][N] = act(in[B][M]) @ W[N][M]^T + b, stored f64; per-block col sum/sumsq.
// MODE 0: in = raw f32 events. MODE 1: in = f64 h_prev, act = relu(in*a+c).
// Epilogue uses probe-measured maps -> NO layout assumption.
template<int M, int N, int MODE>
__global__ __launch_bounds__(256, 3) void gemm_mfma(
    const void* __restrict__ inv, const float* __restrict__ W,
    const float* __restrict__ bias,
    const double* __restrict__ bna, const double* __restrict__ bnc,
    const unsigned* __restrict__ maps_g,
    double* __restrict__ hout, double* __restrict__ partials)
{
  constexpr int BK = 16;
  constexpr int NT = (N + 15) / 16;
  constexpr int NPAD = NT * 16;
  constexpr int NCH = (M + BK - 1) / BK;

  __shared__ double XS[64][BK + 1];          // X tile (post-act), padded
  __shared__ double WS[BK][NPAD + 1];        // W^T chunk: WS[kk][j] = W[j][k0+kk]
  __shared__ double TT[4][16][17];           // per-wave true-(row,col) D tile

  const int tid = threadIdx.x;
  const int w = tid >> 6;                    // wave 0..3
  const int l = tid & 63;
  const int lr = l & 15;
  const int lk = l >> 4;
  const long i0 = (long)blockIdx.x * 64;
  const int wrow = w * 16;
  const unsigned um = maps_g[l];             // D layout LUT for this lane

  f64x4 acc[NT];
  #pragma unroll
  for (int t = 0; t < NT; ++t) acc[t] = (f64x4){0.0, 0.0, 0.0, 0.0};

  for (int ch = 0; ch < NCH; ++ch) {
    const int k0 = ch * BK;
    // ---- stage X tile (apply act for MODE 1), zero-pad k >= M ----
    for (int idx = tid; idx < 64 * BK; idx += 256) {
      int r = idx >> 4, kk = idx & 15;
      int k = k0 + kk;
      double v = 0.0;
      if (k < M) {
        if constexpr (MODE == 0) {
          v = (double)((const float*)inv)[(i0 + r) * (long)M + k];
        } else {
          v = ((const double*)inv)[(i0 + r) * (long)M + k];
          v = v * bna[k] + bnc[k];
          v = v > 0.0 ? v : 0.0;
        }
      }
      XS[r][kk] = v;
    }
    // ---- stage W^T chunk, zero-pad j >= N or k >= M ----
    for (int idx = tid; idx < BK * NPAD; idx += 256) {
      int kk = idx & 15, j = idx >> 4;
      int k = k0 + kk;
      WS[kk][j] = (j < N && k < M) ? (double)W[(long)j * M + k] : 0.0;
    }
    __syncthreads();
    // ---- 4 MFMA k-steps of 4 ----
    #pragma unroll
    for (int ks = 0; ks < 4; ++ks) {
      double aA = XS[wrow + lr][ks * 4 + lk];
      #pragma unroll
      for (int t = 0; t < NT; ++t) {
        double bB = WS[ks * 4 + lk][t * 16 + lr];
        acc[t] = __builtin_amdgcn_mfma_f64_16x16x4f64(aA, bB, acc[t], 0, 0, 0);
      }
    }
    __syncthreads();
  }

  // ---- epilogue: map-driven LDS transpose, then store + column stats ----
  double* pp = partials + (long)blockIdx.x * (2 * N);
  for (int t = 0; t < NT; ++t) {
    __syncthreads();                         // TT free (prev t consumed)
    #pragma unroll
    for (int r = 0; r < 4; ++r) {
      unsigned b = (um >> (8 * r)) & 0xffu;
      TT[w][b >> 4][b & 15] = acc[t][r];
    }
    __syncthreads();
    // store h (+bias) from true-layout tile
    for (int idx = tid; idx < 1024; idx += 256) {
      int rb = idx >> 4, j16 = idx & 15;
      int j = t * 16 + j16;
      if (j < N) {
        double h = TT[rb >> 4][rb & 15][j16] + (double)bias[j];
        hout[(i0 + rb) * (long)N + j] = h;
      }
    }
    // column stats: 64 threads, 4 partials of 16 rows each, shfl-combine
    if (tid < 64) {
      int j16 = tid >> 2, part = tid & 3;
      int j = t * 16 + j16;
      double s = 0.0, q = 0.0;
      if (j < N) {
        double bj = (double)bias[j];
        #pragma unroll
        for (int rr = 0; rr < 16; ++rr) {
          int rb = part * 16 + rr;
          double h = TT[rb >> 4][rb & 15][j16] + bj;
          s += h; q += h * h;
        }
      }
      s += __shfl_xor(s, 1); s += __shfl_xor(s, 2);
      q += __shfl_xor(q, 1); q += __shfl_xor(q, 2);
      if (part == 0 && j < N) { pp[j] = s; pp[N + j] = q; }
    }
  }
}

// final: BN+ReLU(h4) -> Linear(50->64) -> sigmoid -> sample -> logsum
__global__ __launch_bounds__(256) void final_store(
    const double* __restrict__ h4,
    const double* __restrict__ bna, const double* __restrict__ bnc,
    const float* __restrict__ W5, const float* __restrict__ b5,
    float* __restrict__ out0, float* __restrict__ out1)
{
  __shared__ double A5[ROWS][51];
  __shared__ double W5S[50][65];
  __shared__ double T[ROWS][65];
  const int tid = threadIdx.x;
  const int c = tid & 63, g = tid >> 6;
  const long i0 = (long)blockIdx.x * ROWS;

  for (int idx = tid; idx < ROWS * 50; idx += 256) {
    int r = idx / 50, k = idx % 50;
    double v = h4[(i0 + r) * 50 + k] * bna[k] + bnc[k];
    A5[r][k] = v > 0.0 ? v : 0.0;
  }
  for (int idx = tid; idx < 64 * 50; idx += 256) {
    int j = idx / 50, k = idx % 50;
    W5S[k][j] = (double)W5[j * 50 + k];
  }
  __syncthreads();

  double acc[8];
  #pragma unroll
  for (int rr = 0; rr < 8; ++rr) acc[rr] = 0.0;
  for (int k = 0; k < 50; ++k) {
    double w = W5S[k][c];
    #pragma unroll
    for (int rr = 0; rr < 8; ++rr) acc[rr] += A5[g * 8 + rr][k] * w;
  }
  double bj = (double)b5[c];
  #pragma unroll
  for (int rr = 0; rr < 8; ++rr) {
    int r = g * 8 + rr;
    double h = acc[rr] + bj;
    double p = 1.0 / (1.0 + exp(-h));
    float uf = jax_uniform((unsigned)((i0 + r) * 64 + c));
    bool ch = ((double)uf < 1.0 - p);
    out0[(i0 + r) * 64 + c] = ch ? 0.0f : 1.0f;
    T[r][c] = log(ch ? (1.0 - p) : p);
  }
  __syncthreads();
  for (int r = tid; r < ROWS; r += 256) {
    double s = 0.0;
    for (int j = 0; j < 64; ++j) s += T[r][j];
    out1[i0 + r] = (float)s;
  }
}

// ======================= FALLBACK: recompute chain (verified) ==============
template<int M, int N>
__device__ __forceinline__ void step_gemm(const double* IN, const float* __restrict__ W,
                                          int tid, double* acc) {
  if (tid < N) {
    #pragma unroll
    for (int r = 0; r < 32; ++r) acc[r] = 0.0;
    for (int k = 0; k < M; ++k) {
      double wv = (double)W[tid * M + k];
      #pragma unroll
      for (int r = 0; r < 32; ++r) acc[r] += IN[r * M + k] * wv;
    }
  }
}

template<int N>
__device__ __forceinline__ void step_write(double* OUT, const double* acc,
                                           const float* __restrict__ b, int tid) {
  if (tid < N) {
    double bj = (double)b[tid];
    #pragma unroll
    for (int r = 0; r < 32; ++r) OUT[r * N + tid] = acc[r] + bj;
  }
}

template<int N>
__device__ __forceinline__ void step_stats(const double* acc, const float* __restrict__ b,
                                           double* partials, int blk, int tid) {
  if (tid < N) {
    double bj = (double)b[tid], s = 0.0, q = 0.0;
    #pragma unroll
    for (int r = 0; r < 32; ++r) { double h = acc[r] + bj; s += h; q += h * h; }
    double* pp = partials + (long)blk * (2 * N);
    pp[tid] = s; pp[N + tid] = q;
  }
}

template<int N>
__device__ __forceinline__ void apply_bn(double* BUF, const double* __restrict__ a,
                                         const double* __restrict__ c, int tid) {
  for (int idx = tid; idx < 32 * N; idx += 256) {
    int col = idx % N;
    double v = BUF[idx] * a[col] + c[col];
    BUF[idx] = v > 0.0 ? v : 0.0;
  }
}

template<int PL>
__global__ __launch_bounds__(256) void chain_pass(
    const float* __restrict__ ev,
    const float* __restrict__ W0, const float* __restrict__ b0,
    const float* __restrict__ W1, const float* __restrict__ b1,
    const float* __restrict__ W2, const float* __restrict__ b2,
    const float* __restrict__ W3, const float* __restrict__ b3,
    const float* __restrict__ W4, const float* __restrict__ b4,
    const float* __restrict__ W5, const float* __restrict__ b5,
    const double* __restrict__ bn_a, const double* __restrict__ bn_c,
    double* __restrict__ partials,
    float* __restrict__ out0, float* __restrict__ out1)
{
  __shared__ double SA[32 * 130];
  __shared__ double SB[32 * 110];
  const int tid = threadIdx.x;
  const int blk = blockIdx.x;
  const long i0 = (long)blk * 32;
  double acc[32];

  {
    float* evf = (float*)SA;
    if (tid < 130) {
      #pragma unroll
      for (int r = 0; r < 32; ++r) acc[r] = 0.0;
    }
    for (int c = 0; c < 4; ++c) {
      __syncthreads();
      for (int idx = tid; idx < 32 * 256; idx += 256) {
        int r = idx >> 8, kk = idx & 255;
        evf[idx] = ev[(i0 + r) * 1024 + c * 256 + kk];
      }
      __syncthreads();
      if (tid < 130) {
        for (int kk = 0; kk < 256; ++kk) {
          double wv = (double)W0[tid * 1024 + c * 256 + kk];
          #pragma unroll
          for (int r = 0; r < 32; ++r) acc[r] += (double)evf[r * 256 + kk] * wv;
        }
      }
    }
    __syncthreads();
    if constexpr (PL == 0) { step_stats<130>(acc, b0, partials, blk, tid); return; }
    step_write<130>(SA, acc, b0, tid);
    __syncthreads();
    apply_bn<130>(SA, bn_a + 0, bn_c + 0, tid);
    __syncthreads();
  }
  if constexpr (PL >= 1) {
    step_gemm<130, 110>(SA, W1, tid, acc);
    if constexpr (PL == 1) { step_stats<110>(acc, b1, partials, blk, tid); return; }
    __syncthreads();
    step_write<110>(SB, acc, b1, tid);
    __syncthreads();
    apply_bn<110>(SB, bn_a + 130, bn_c + 130, tid);
    __syncthreads();
  }
  if constexpr (PL >= 2) {
    step_gemm<110, 90>(SB, W2, tid, acc);
    if constexpr (PL == 2) { step_stats<90>(acc, b2, partials, blk, tid); return; }
    __syncthreads();
    step_write<90>(SA, acc, b2, tid);
    __syncthreads();
    apply_bn<90>(SA, bn_a + 240, bn_c + 240, tid);
    __syncthreads();
  }
  if constexpr (PL >= 3) {
    step_gemm<90, 70>(SA, W3, tid, acc);
    if constexpr (PL == 3) { step_stats<70>(acc, b3, partials, blk, tid); return; }
    __syncthreads();
    step_write<70>(SB, acc, b3, tid);
    __syncthreads();
    apply_bn<70>(SB, bn_a + 330, bn_c + 330, tid);
    __syncthreads();
  }
  if constexpr (PL >= 4) {
    step_gemm<70, 50>(SB, W4, tid, acc);
    if constexpr (PL == 4) { step_stats<50>(acc, b4, partials, blk, tid); return; }
    __syncthreads();
    step_write<50>(SA, acc, b4, tid);
    __syncthreads();
    apply_bn<50>(SA, bn_a + 400, bn_c + 400, tid);
    __syncthreads();
  }
  if constexpr (PL == 5) {
    if (tid < 64) {
      #pragma unroll
      for (int r = 0; r < 32; ++r) acc[r] = 0.0;
      for (int k = 0; k < 50; ++k) {
        double wv = (double)W5[tid * 50 + k];
        #pragma unroll
        for (int r = 0; r < 32; ++r) acc[r] += SA[r * 50 + k] * wv;
      }
      double bj = (double)b5[tid];
      #pragma unroll
      for (int r = 0; r < 32; ++r) {
        double h = acc[r] + bj;
        double p = 1.0 / (1.0 + exp(-h));
        float uf = jax_uniform((unsigned)((i0 + r) * 64 + tid));
        bool ch = ((double)uf < 1.0 - p);
        out0[(i0 + r) * 64 + tid] = ch ? 0.0f : 1.0f;
        double d = ch ? (1.0 - p) : p;
        SB[r * 64 + tid] = log(d);
      }
    }
    __syncthreads();
    if (tid < 32) {
      double s = 0.0;
      for (int j = 0; j < 64; ++j) s += SB[tid * 64 + j];
      out1[i0 + tid] = (float)s;
    }
  }
}

// ---------------- BN stats finalize: partials -> a, c ----------------
template<int N>
__global__ __launch_bounds__(256) void bn_finalize2(
    const double* __restrict__ partials, int nblocks,
    const float* __restrict__ g, const float* __restrict__ be,
    double* __restrict__ a, double* __restrict__ c)
{
  const int j = blockIdx.x;
  const int tid = threadIdx.x;
  double s = 0.0, q = 0.0;
  for (int b = tid; b < nblocks; b += 256) {
    const double* p = partials + (long)b * (2 * N);
    s += p[j];
    q += p[N + j];
  }
  __shared__ double ls[256], lq[256];
  ls[tid] = s; lq[tid] = q;
  __syncthreads();
  for (int off = 128; off > 0; off >>= 1) {
    if (tid < off) { ls[tid] += ls[tid + off]; lq[tid] += lq[tid + off]; }
    __syncthreads();
  }
  if (tid == 0) {
    double mu  = ls[0] * (1.0 / 131072.0);
    double var = lq[0] * (1.0 / 131072.0) - mu * mu;
    double aj  = (double)g[j] / sqrt(var + 1e-5);
    a[j] = aj;
    c[j] = (double)be[j] - mu * aj;
  }
}

// ---------------- host side ----------------
extern "C" void kernel_launch(void* const* d_in, const int* in_sizes, int n_in,
                              void* d_out, int out_size, void* d_ws, size_t ws_size,
                              hipStream_t stream)
{
  const float* F[23];
  for (int i = 0; i < 23; ++i) F[i] = (const float*)d_in[i];
  const float* ev = F[0];
  float* out0 = (float*)d_out;
  float* out1 = out0 + BATCH * 64;

  // partials live in d_out (consumed before the final pass overwrites it)
  double* partials = (double*)d_out;
  double* bn_a = (double*)d_ws;          // 450 doubles
  double* bn_c = bn_a + 450;             // 450 doubles
  unsigned* maps = (unsigned*)(bn_c + 450);  // 64 u32

  char* ws = (char*)d_ws;
  size_t used = (size_t)((char*)(maps + 64) - ws);
  used = (used + 255) & ~(size_t)255;
  const size_t needA = (size_t)BATCH * 130 * 8;   // 136.3 MB
  const size_t needB = (size_t)BATCH * 110 * 8;   // 115.3 MB

  dim3 b(256);

  if (ws_size >= used + needA + needB) {
    // ---------- fast stored-h path (f64 MFMA, probe-measured layout) ----------
    double* bufA = (double*)(ws + used);
    double* bufB = (double*)(ws + used + needA);
    dim3 g(GBLOCKS);
    probe_layout<<<dim3(1), dim3(64), 0, stream>>>(maps);
    gemm_mfma<1024, 130, 0><<<g, b, 0, stream>>>(ev, F[1], F[2],
        nullptr, nullptr, maps, bufA, partials);
    bn_finalize2<130><<<dim3(130), b, 0, stream>>>(partials, GBLOCKS, F[3], F[4], bn_a + 0, bn_c + 0);
    gemm_mfma<130, 110, 1><<<g, b, 0, stream>>>(bufA, F[5], F[6],
        bn_a + 0, bn_c + 0, maps, bufB, partials);
    bn_finalize2<110><<<dim3(110), b, 0, stream>>>(partials, GBLOCKS, F[7], F[8], bn_a + 130, bn_c + 130);
    gemm_mfma<110, 90, 1><<<g, b, 0, stream>>>(bufB, F[9], F[10],
        bn_a + 130, bn_c + 130, maps, bufA, partials);
    bn_finalize2<90><<<dim3(90), b, 0, stream>>>(partials, GBLOCKS, F[11], F[12], bn_a + 240, bn_c + 240);
    gemm_mfma<90, 70, 1><<<g, b, 0, stream>>>(bufA, F[13], F[14],
        bn_a + 240, bn_c + 240, maps, bufB, partials);
    bn_finalize2<70><<<dim3(70), b, 0, stream>>>(partials, GBLOCKS, F[15], F[16], bn_a + 330, bn_c + 330);
    gemm_mfma<70, 50, 1><<<g, b, 0, stream>>>(bufB, F[17], F[18],
        bn_a + 330, bn_c + 330, maps, bufA, partials);
    bn_finalize2<50><<<dim3(50), b, 0, stream>>>(partials, GBLOCKS, F[19], F[20], bn_a + 400, bn_c + 400);
    final_store<<<dim3(NBLOCKS), b, 0, stream>>>(bufA, bn_a + 400, bn_c + 400, F[21], F[22], out0, out1);
  } else {
    // ---------- fallback: verified recompute chain ----------
    dim3 g(NBLOCKS);
#define ARGS ev, F[1],F[2], F[5],F[6], F[9],F[10], F[13],F[14], F[17],F[18], \
             F[21],F[22], bn_a, bn_c, partials, out0, out1
    chain_pass<0><<<g, b, 0, stream>>>(ARGS);
    bn_finalize2<130><<<dim3(130), b, 0, stream>>>(partials, NBLOCKS, F[3],  F[4],  bn_a + 0,   bn_c + 0);
    chain_pass<1><<<g, b, 0, stream>>>(ARGS);
    bn_finalize2<110><<<dim3(110), b, 0, stream>>>(partials, NBLOCKS, F[7],  F[8],  bn_a + 130, bn_c + 130);
    chain_pass<2><<<g, b, 0, stream>>>(ARGS);
    bn_finalize2<90><<<dim3(90),  b, 0, stream>>>(partials, NBLOCKS, F[11], F[12], bn_a + 240, bn_c + 240);
    chain_pass<3><<<g, b, 0, stream>>>(ARGS);
    bn_finalize2<70><<<dim3(70),  b, 0, stream>>>(partials, NBLOCKS, F[15], F[16], bn_a + 330, bn_c + 330);
    chain_pass<4><<<g, b, 0, stream>>>(ARGS);
    bn_finalize2<50><<<dim3(50),  b, 0, stream>>>(partials, NBLOCKS, F[19], F[20], bn_a + 400, bn_c + 400);
    chain_pass<5><<<g, b, 0, stream>>>(ARGS);
#undef ARGS
  }
}

// Round 8
// 1135.755 us; speedup vs baseline: 17.0418x; 1.3706x over previous
//
#include <hip/hip_runtime.h>
#include <type_traits>

// ---------------- problem constants ----------------
static const long BATCH = 131072;
static const int ROWS = 32;                  // rows per block (final/fallback)
static const int NBLOCKS = 4096;             // fallback/final grid
static const int GBLOCKS = 2048;             // gemm_mfma grid (64 rows each)

using f64x4 = __attribute__((ext_vector_type(4))) double;

// ---------------- threefry2x32 (JAX partitionable, key = (0, 42)) ----------
__device__ __forceinline__ unsigned rotl32(unsigned x, int d) {
  return (x << d) | (x >> (32 - d));
}

struct U2 { unsigned a, b; };

__device__ __forceinline__ U2 threefry(unsigned x0, unsigned x1) {
  const unsigned ks0 = 0u, ks1 = 42u, ks2 = 0u ^ 42u ^ 0x1BD11BDAu;
  x0 += ks0; x1 += ks1;
#define TF_R4(A,B,C,D) \
  x0 += x1; x1 = rotl32(x1, A); x1 ^= x0; \
  x0 += x1; x1 = rotl32(x1, B); x1 ^= x0; \
  x0 += x1; x1 = rotl32(x1, C); x1 ^= x0; \
  x0 += x1; x1 = rotl32(x1, D); x1 ^= x0;
  TF_R4(13,15,26,6)  x0 += ks1; x1 += ks2 + 1u;
  TF_R4(17,29,16,24) x0 += ks2; x1 += ks0 + 2u;
  TF_R4(13,15,26,6)  x0 += ks0; x1 += ks1 + 3u;
  TF_R4(17,29,16,24) x0 += ks1; x1 += ks2 + 4u;
  TF_R4(13,15,26,6)  x0 += ks2; x1 += ks0 + 5u;
#undef TF_R4
  U2 r; r.a = x0; r.b = x1; return r;
}

// partitionable 32-bit draw: bits1 ^ bits2  (VERIFIED passing, round 4)
__device__ __forceinline__ float jax_uniform(unsigned idx) {
  U2 r = threefry(0u, idx);
  unsigned bits = r.a ^ r.b;
  unsigned fb = (bits >> 9) | 0x3f800000u;
  return __uint_as_float(fb) - 1.0f;
}

// ============ f64-MFMA D-fragment layout probe (VERIFIED round 7) ==========
__global__ __launch_bounds__(64) void probe_layout(unsigned* __restrict__ maps) {
  __shared__ double X1[16][5], X2[16][5], W1s[4][17], W2s[4][17];
  const int l = threadIdx.x;
  const int lr = l & 15, lk = l >> 4;
  {
    int i = l >> 2, k = l & 3;
    X1[i][k] = (k == 0) ? (double)i : 0.0;   // D1[i][j] = i
    X2[i][k] = (k == 0) ? 1.0 : 0.0;         // D2[i][j] = j
    W1s[k][i] = (k == 0) ? 1.0 : 0.0;
    W2s[k][i] = (k == 0) ? (double)i : 0.0;
  }
  __syncthreads();
  f64x4 a1 = {0.0, 0.0, 0.0, 0.0}, a2 = {0.0, 0.0, 0.0, 0.0};
  a1 = __builtin_amdgcn_mfma_f64_16x16x4f64(X1[lr][lk], W1s[lk][lr], a1, 0, 0, 0);
  a2 = __builtin_amdgcn_mfma_f64_16x16x4f64(X2[lr][lk], W2s[lk][lr], a2, 0, 0, 0);
  unsigned m = 0;
  #pragma unroll
  for (int r = 0; r < 4; ++r) {
    int row = (int)(a1[r] + 0.5);
    int col = (int)(a2[r] + 0.5);
    m |= (unsigned)(((row & 15) << 4) | (col & 15)) << (8 * r);
  }
  maps[l] = m;
}

// ======================= FAST PATH: f64-MFMA GEMM (pipelined) ==============
// h[B][N] = act(in[B][M]) @ W[N][M]^T + b, stored f64; per-block col sum/sumsq.
// MODE 0: in = raw f32 events (X staged f32). MODE 1: in = f64 h_prev,
// act = relu(in*a+c) (X staged f64 for exactness). W staged f32 always,
// converted f64 at read. Register-prefetch double buffer hides load latency.
template<int M, int N, int MODE>
__global__ __launch_bounds__(256, 4) void gemm_mfma(
    const void* __restrict__ inv, const float* __restrict__ W,
    const float* __restrict__ bias,
    const double* __restrict__ bna, const double* __restrict__ bnc,
    const unsigned* __restrict__ maps_g,
    double* __restrict__ hout, double* __restrict__ partials)
{
  constexpr int BK = 16;
  constexpr int NT = (N + 15) / 16;
  constexpr int NPAD = NT * 16;
  constexpr int NCH = (M + BK - 1) / BK;
  constexpr int NW = BK * NPAD;               // W elems per chunk
  constexpr int WLD = (NW + 255) / 256;       // per-thread W loads

  struct SM0 { float  xs[64][17]; float ws[BK][NPAD + 1]; };
  struct SM1 { double xs[64][17]; float ws[BK][NPAD + 1]; };
  using SMX = typename std::conditional<MODE == 0, SM0, SM1>::type;
  union SMEM { SMX m; double tt[4][16][17]; };
  __shared__ SMEM sm;

  const int tid = threadIdx.x;
  const int w = tid >> 6;
  const int l = tid & 63;
  const int lr = l & 15;
  const int lk = l >> 4;
  const long i0 = (long)blockIdx.x * 64;
  const int wrow = w * 16;
  const unsigned um = maps_g[l];

  // prefetch registers
  float xf[4]; double xd[4]; float wf[WLD];

  auto load_chunk = [&](int k0) {
    #pragma unroll
    for (int p = 0; p < 4; ++p) {
      int idx = tid + p * 256;
      int r = idx >> 4, kk = idx & 15;
      int k = k0 + kk;
      if constexpr (MODE == 0) {
        xf[p] = (k < M) ? ((const float*)inv)[(i0 + r) * (long)M + k] : 0.0f;
      } else {
        double v = 0.0;
        if (k < M) {
          v = ((const double*)inv)[(i0 + r) * (long)M + k];
          v = v * bna[k] + bnc[k];
          v = v > 0.0 ? v : 0.0;
        }
        xd[p] = v;
      }
    }
    #pragma unroll
    for (int p = 0; p < WLD; ++p) {
      int idx = tid + p * 256;
      float v = 0.0f;
      if (idx < NW) {
        int kk = idx & 15, j = idx >> 4;
        int k = k0 + kk;
        if (j < N && k < M) v = W[(long)j * M + k];
      }
      wf[p] = v;
    }
  };

  auto write_chunk = [&]() {
    #pragma unroll
    for (int p = 0; p < 4; ++p) {
      int idx = tid + p * 256;
      int r = idx >> 4, kk = idx & 15;
      if constexpr (MODE == 0) sm.m.xs[r][kk] = xf[p];
      else                     sm.m.xs[r][kk] = xd[p];
    }
    #pragma unroll
    for (int p = 0; p < WLD; ++p) {
      int idx = tid + p * 256;
      if (idx < NW) {
        int kk = idx & 15, j = idx >> 4;
        sm.m.ws[kk][j] = wf[p];
      }
    }
  };

  f64x4 acc[NT];
  #pragma unroll
  for (int t = 0; t < NT; ++t) acc[t] = (f64x4){0.0, 0.0, 0.0, 0.0};

  load_chunk(0);
  for (int ch = 0; ch < NCH; ++ch) {
    __syncthreads();                 // previous chunk's LDS reads complete
    write_chunk();
    __syncthreads();                 // LDS ready
    if (ch + 1 < NCH) load_chunk((ch + 1) * BK);   // latency hides under MFMA
    #pragma unroll
    for (int ks = 0; ks < 4; ++ks) {
      double aA = (double)sm.m.xs[wrow + lr][ks * 4 + lk];
      #pragma unroll
      for (int t = 0; t < NT; ++t) {
        double bB = (double)sm.m.ws[ks * 4 + lk][t * 16 + lr];
        acc[t] = __builtin_amdgcn_mfma_f64_16x16x4f64(aA, bB, acc[t], 0, 0, 0);
      }
    }
  }

  // ---- epilogue: map-driven LDS transpose (tt unions staging), store+stats --
  double* pp = partials + (long)blockIdx.x * (2 * N);
  for (int t = 0; t < NT; ++t) {
    __syncthreads();                 // staging/prev-tile reads done
    #pragma unroll
    for (int r = 0; r < 4; ++r) {
      unsigned b = (um >> (8 * r)) & 0xffu;
      sm.tt[w][b >> 4][b & 15] = acc[t][r];
    }
    __syncthreads();
    for (int idx = tid; idx < 1024; idx += 256) {
      int rb = idx >> 4, j16 = idx & 15;
      int j = t * 16 + j16;
      if (j < N) {
        double h = sm.tt[rb >> 4][rb & 15][j16] + (double)bias[j];
        hout[(i0 + rb) * (long)N + j] = h;
      }
    }
    if (tid < 64) {
      int j16 = tid >> 2, part = tid & 3;
      int j = t * 16 + j16;
      double s = 0.0, q = 0.0;
      if (j < N) {
        double bj = (double)bias[j];
        #pragma unroll
        for (int rr = 0; rr < 16; ++rr) {
          int rb = part * 16 + rr;
          double h = sm.tt[rb >> 4][rb & 15][j16] + bj;
          s += h; q += h * h;
        }
      }
      s += __shfl_xor(s, 1); s += __shfl_xor(s, 2);
      q += __shfl_xor(q, 1); q += __shfl_xor(q, 2);
      if (part == 0 && j < N) { pp[j] = s; pp[N + j] = q; }
    }
  }
}

// final: BN+ReLU(h4) -> Linear(50->64) -> sigmoid -> sample -> logsum
__global__ __launch_bounds__(256) void final_store(
    const double* __restrict__ h4,
    const double* __restrict__ bna, const double* __restrict__ bnc,
    const float* __restrict__ W5, const float* __restrict__ b5,
    float* __restrict__ out0, float* __restrict__ out1)
{
  __shared__ double A5[ROWS][51];
  __shared__ double W5S[50][65];
  __shared__ double T[ROWS][65];
  const int tid = threadIdx.x;
  const int c = tid & 63, g = tid >> 6;
  const long i0 = (long)blockIdx.x * ROWS;

  for (int idx = tid; idx < ROWS * 50; idx += 256) {
    int r = idx / 50, k = idx % 50;
    double v = h4[(i0 + r) * 50 + k] * bna[k] + bnc[k];
    A5[r][k] = v > 0.0 ? v : 0.0;
  }
  for (int idx = tid; idx < 64 * 50; idx += 256) {
    int j = idx / 50, k = idx % 50;
    W5S[k][j] = (double)W5[j * 50 + k];
  }
  __syncthreads();

  double acc[8];
  #pragma unroll
  for (int rr = 0; rr < 8; ++rr) acc[rr] = 0.0;
  for (int k = 0; k < 50; ++k) {
    double w = W5S[k][c];
    #pragma unroll
    for (int rr = 0; rr < 8; ++rr) acc[rr] += A5[g * 8 + rr][k] * w;
  }
  double bj = (double)b5[c];
  #pragma unroll
  for (int rr = 0; rr < 8; ++rr) {
    int r = g * 8 + rr;
    double h = acc[rr] + bj;
    double p = 1.0 / (1.0 + exp(-h));
    float uf = jax_uniform((unsigned)((i0 + r) * 64 + c));
    bool ch = ((double)uf < 1.0 - p);
    out0[(i0 + r) * 64 + c] = ch ? 0.0f : 1.0f;
    T[r][c] = log(ch ? (1.0 - p) : p);
  }
  __syncthreads();
  for (int r = tid; r < ROWS; r += 256) {
    double s = 0.0;
    for (int j = 0; j < 64; ++j) s += T[r][j];
    out1[i0 + r] = (float)s;
  }
}

// ======================= FALLBACK: recompute chain (verified) ==============
template<int M, int N>
__device__ __forceinline__ void step_gemm(const double* IN, const float* __restrict__ W,
                                          int tid, double* acc) {
  if (tid < N) {
    #pragma unroll
    for (int r = 0; r < 32; ++r) acc[r] = 0.0;
    for (int k = 0; k < M; ++k) {
      double wv = (double)W[tid * M + k];
      #pragma unroll
      for (int r = 0; r < 32; ++r) acc[r] += IN[r * M + k] * wv;
    }
  }
}

template<int N>
__device__ __forceinline__ void step_write(double* OUT, const double* acc,
                                           const float* __restrict__ b, int tid) {
  if (tid < N) {
    double bj = (double)b[tid];
    #pragma unroll
    for (int r = 0; r < 32; ++r) OUT[r * N + tid] = acc[r] + bj;
  }
}

template<int N>
__device__ __forceinline__ void step_stats(const double* acc, const float* __restrict__ b,
                                           double* partials, int blk, int tid) {
  if (tid < N) {
    double bj = (double)b[tid], s = 0.0, q = 0.0;
    #pragma unroll
    for (int r = 0; r < 32; ++r) { double h = acc[r] + bj; s += h; q += h * h; }
    double* pp = partials + (long)blk * (2 * N);
    pp[tid] = s; pp[N + tid] = q;
  }
}

template<int N>
__device__ __forceinline__ void apply_bn(double* BUF, const double* __restrict__ a,
                                         const double* __restrict__ c, int tid) {
  for (int idx = tid; idx < 32 * N; idx += 256) {
    int col = idx % N;
    double v = BUF[idx] * a[col] + c[col];
    BUF[idx] = v > 0.0 ? v : 0.0;
  }
}

template<int PL>
__global__ __launch_bounds__(256) void chain_pass(
    const float* __restrict__ ev,
    const float* __restrict__ W0, const float* __restrict__ b0,
    const float* __restrict__ W1, const float* __restrict__ b1,
    const float* __restrict__ W2, const float* __restrict__ b2,
    const float* __restrict__ W3, const float* __restrict__ b3,
    const float* __restrict__ W4, const float* __restrict__ b4,
    const float* __restrict__ W5, const float* __restrict__ b5,
    const double* __restrict__ bn_a, const double* __restrict__ bn_c,
    double* __restrict__ partials,
    float* __restrict__ out0, float* __restrict__ out1)
{
  __shared__ double SA[32 * 130];
  __shared__ double SB[32 * 110];
  const int tid = threadIdx.x;
  const int blk = blockIdx.x;
  const long i0 = (long)blk * 32;
  double acc[32];

  {
    float* evf = (float*)SA;
    if (tid < 130) {
      #pragma unroll
      for (int r = 0; r < 32; ++r) acc[r] = 0.0;
    }
    for (int c = 0; c < 4; ++c) {
      __syncthreads();
      for (int idx = tid; idx < 32 * 256; idx += 256) {
        int r = idx >> 8, kk = idx & 255;
        evf[idx] = ev[(i0 + r) * 1024 + c * 256 + kk];
      }
      __syncthreads();
      if (tid < 130) {
        for (int kk = 0; kk < 256; ++kk) {
          double wv = (double)W0[tid * 1024 + c * 256 + kk];
          #pragma unroll
          for (int r = 0; r < 32; ++r) acc[r] += (double)evf[r * 256 + kk] * wv;
        }
      }
    }
    __syncthreads();
    if constexpr (PL == 0) { step_stats<130>(acc, b0, partials, blk, tid); return; }
    step_write<130>(SA, acc, b0, tid);
    __syncthreads();
    apply_bn<130>(SA, bn_a + 0, bn_c + 0, tid);
    __syncthreads();
  }
  if constexpr (PL >= 1) {
    step_gemm<130, 110>(SA, W1, tid, acc);
    if constexpr (PL == 1) { step_stats<110>(acc, b1, partials, blk, tid); return; }
    __syncthreads();
    step_write<110>(SB, acc, b1, tid);
    __syncthreads();
    apply_bn<110>(SB, bn_a + 130, bn_c + 130, tid);
    __syncthreads();
  }
  if constexpr (PL >= 2) {
    step_gemm<110, 90>(SB, W2, tid, acc);
    if constexpr (PL == 2) { step_stats<90>(acc, b2, partials, blk, tid); return; }
    __syncthreads();
    step_write<90>(SA, acc, b2, tid);
    __syncthreads();
    apply_bn<90>(SA, bn_a + 240, bn_c + 240, tid);
    __syncthreads();
  }
  if constexpr (PL >= 3) {
    step_gemm<90, 70>(SA, W3, tid, acc);
    if constexpr (PL == 3) { step_stats<70>(acc, b3, partials, blk, tid); return; }
    __syncthreads();
    step_write<70>(SB, acc, b3, tid);
    __syncthreads();
    apply_bn<70>(SB, bn_a + 330, bn_c + 330, tid);
    __syncthreads();
  }
  if constexpr (PL >= 4) {
    step_gemm<70, 50>(SB, W4, tid, acc);
    if constexpr (PL == 4) { step_stats<50>(acc, b4, partials, blk, tid); return; }
    __syncthreads();
    step_write<50>(SA, acc, b4, tid);
    __syncthreads();
    apply_bn<50>(SA, bn_a + 400, bn_c + 400, tid);
    __syncthreads();
  }
  if constexpr (PL == 5) {
    if (tid < 64) {
      #pragma unroll
      for (int r = 0; r < 32; ++r) acc[r] = 0.0;
      for (int k = 0; k < 50; ++k) {
        double wv = (double)W5[tid * 50 + k];
        #pragma unroll
        for (int r = 0; r < 32; ++r) acc[r] += SA[r * 50 + k] * wv;
      }
      double bj = (double)b5[tid];
      #pragma unroll
      for (int r = 0; r < 32; ++r) {
        double h = acc[r] + bj;
        double p = 1.0 / (1.0 + exp(-h));
        float uf = jax_uniform((unsigned)((i0 + r) * 64 + tid));
        bool ch = ((double)uf < 1.0 - p);
        out0[(i0 + r) * 64 + tid] = ch ? 0.0f : 1.0f;
        double d = ch ? (1.0 - p) : p;
        SB[r * 64 + tid] = log(d);
      }
    }
    __syncthreads();
    if (tid < 32) {
      double s = 0.0;
      for (int j = 0; j < 64; ++j) s += SB[tid * 64 + j];
      out1[i0 + tid] = (float)s;
    }
  }
}

// ---------------- BN stats finalize: partials -> a, c ----------------
template<int N>
__global__ __launch_bounds__(256) void bn_finalize2(
    const double* __restrict__ partials, int nblocks,
    const float* __restrict__ g, const float* __restrict__ be,
    double* __restrict__ a, double* __restrict__ c)
{
  const int j = blockIdx.x;
  const int tid = threadIdx.x;
  double s = 0.0, q = 0.0;
  for (int b = tid; b < nblocks; b += 256) {
    const double* p = partials + (long)b * (2 * N);
    s += p[j];
    q += p[N + j];
  }
  __shared__ double ls[256], lq[256];
  ls[tid] = s; lq[tid] = q;
  __syncthreads();
  for (int off = 128; off > 0; off >>= 1) {
    if (tid < off) { ls[tid] += ls[tid + off]; lq[tid] += lq[tid + off]; }
    __syncthreads();
  }
  if (tid == 0) {
    double mu  = ls[0] * (1.0 / 131072.0);
    double var = lq[0] * (1.0 / 131072.0) - mu * mu;
    double aj  = (double)g[j] / sqrt(var + 1e-5);
    a[j] = aj;
    c[j] = (double)be[j] - mu * aj;
  }
}

// ---------------- host side ----------------
extern "C" void kernel_launch(void* const* d_in, const int* in_sizes, int n_in,
                              void* d_out, int out_size, void* d_ws, size_t ws_size,
                              hipStream_t stream)
{
  const float* F[23];
  for (int i = 0; i < 23; ++i) F[i] = (const float*)d_in[i];
  const float* ev = F[0];
  float* out0 = (float*)d_out;
  float* out1 = out0 + BATCH * 64;

  // partials live in d_out (consumed before the final pass overwrites it)
  double* partials = (double*)d_out;
  double* bn_a = (double*)d_ws;          // 450 doubles
  double* bn_c = bn_a + 450;             // 450 doubles
  unsigned* maps = (unsigned*)(bn_c + 450);  // 64 u32

  char* ws = (char*)d_ws;
  size_t used = (size_t)((char*)(maps + 64) - ws);
  used = (used + 255) & ~(size_t)255;
  const size_t needA = (size_t)BATCH * 130 * 8;   // 136.3 MB
  const size_t needB = (size_t)BATCH * 110 * 8;   // 115.3 MB

  dim3 b(256);

  if (ws_size >= used + needA + needB) {
    // ---------- fast stored-h path (f64 MFMA, probe-measured layout) ----------
    double* bufA = (double*)(ws + used);
    double* bufB = (double*)(ws + used + needA);
    dim3 g(GBLOCKS);
    probe_layout<<<dim3(1), dim3(64), 0, stream>>>(maps);
    gemm_mfma<1024, 130, 0><<<g, b, 0, stream>>>(ev, F[1], F[2],
        nullptr, nullptr, maps, bufA, partials);
    bn_finalize2<130><<<dim3(130), b, 0, stream>>>(partials, GBLOCKS, F[3], F[4], bn_a + 0, bn_c + 0);
    gemm_mfma<130, 110, 1><<<g, b, 0, stream>>>(bufA, F[5], F[6],
        bn_a + 0, bn_c + 0, maps, bufB, partials);
    bn_finalize2<110><<<dim3(110), b, 0, stream>>>(partials, GBLOCKS, F[7], F[8], bn_a + 130, bn_c + 130);
    gemm_mfma<110, 90, 1><<<g, b, 0, stream>>>(bufB, F[9], F[10],
        bn_a + 130, bn_c + 130, maps, bufA, partials);
    bn_finalize2<90><<<dim3(90), b, 0, stream>>>(partials, GBLOCKS, F[11], F[12], bn_a + 240, bn_c + 240);
    gemm_mfma<90, 70, 1><<<g, b, 0, stream>>>(bufA, F[13], F[14],
        bn_a + 240, bn_c + 240, maps, bufB, partials);
    bn_finalize2<70><<<dim3(70), b, 0, stream>>>(partials, GBLOCKS, F[15], F[16], bn_a + 330, bn_c + 330);
    gemm_mfma<70, 50, 1><<<g, b, 0, stream>>>(bufB, F[17], F[18],
        bn_a + 330, bn_c + 330, maps, bufA, partials);
    bn_finalize2<50><<<dim3(50), b, 0, stream>>>(partials, GBLOCKS, F[19], F[20], bn_a + 400, bn_c + 400);
    final_store<<<dim3(NBLOCKS), b, 0, stream>>>(bufA, bn_a + 400, bn_c + 400, F[21], F[22], out0, out1);
  } else {
    // ---------- fallback: verified recompute chain ----------
    dim3 g(NBLOCKS);
#define ARGS ev, F[1],F[2], F[5],F[6], F[9],F[10], F[13],F[14], F[17],F[18], \
             F[21],F[22], bn_a, bn_c, partials, out0, out1
    chain_pass<0><<<g, b, 0, stream>>>(ARGS);
    bn_finalize2<130><<<dim3(130), b, 0, stream>>>(partials, NBLOCKS, F[3],  F[4],  bn_a + 0,   bn_c + 0);
    chain_pass<1><<<g, b, 0, stream>>>(ARGS);
    bn_finalize2<110><<<dim3(110), b, 0, stream>>>(partials, NBLOCKS, F[7],  F[8],  bn_a + 130, bn_c + 130);
    chain_pass<2><<<g, b, 0, stream>>>(ARGS);
    bn_finalize2<90><<<dim3(90),  b, 0, stream>>>(partials, NBLOCKS, F[11], F[12], bn_a + 240, bn_c + 240);
    chain_pass<3><<<g, b, 0, stream>>>(ARGS);
    bn_finalize2<70><<<dim3(70),  b, 0, stream>>>(partials, NBLOCKS, F[15], F[16], bn_a + 330, bn_c + 330);
    chain_pass<4><<<g, b, 0, stream>>>(ARGS);
    bn_finalize2<50><<<dim3(50),  b, 0, stream>>>(partials, NBLOCKS, F[19], F[20], bn_a + 400, bn_c + 400);
    chain_pass<5><<<g, b, 0, stream>>>(ARGS);
#undef ARGS
  }
}

// Round 9
// 1077.928 us; speedup vs baseline: 17.9561x; 1.0536x over previous
//
#include <hip/hip_runtime.h>
#include <type_traits>

// ---------------- problem constants ----------------
static const long BATCH = 131072;
static const int ROWS = 32;                  // rows per block (final/fallback)
static const int NBLOCKS = 4096;             // fallback/final grid
static const int GBLOCKS = 2048;             // gemm_mfma grid (64 rows each)

using f64x4 = __attribute__((ext_vector_type(4))) double;

// ---------------- threefry2x32 (JAX partitionable, key = (0, 42)) ----------
__device__ __forceinline__ unsigned rotl32(unsigned x, int d) {
  return (x << d) | (x >> (32 - d));
}

struct U2 { unsigned a, b; };

__device__ __forceinline__ U2 threefry(unsigned x0, unsigned x1) {
  const unsigned ks0 = 0u, ks1 = 42u, ks2 = 0u ^ 42u ^ 0x1BD11BDAu;
  x0 += ks0; x1 += ks1;
#define TF_R4(A,B,C,D) \
  x0 += x1; x1 = rotl32(x1, A); x1 ^= x0; \
  x0 += x1; x1 = rotl32(x1, B); x1 ^= x0; \
  x0 += x1; x1 = rotl32(x1, C); x1 ^= x0; \
  x0 += x1; x1 = rotl32(x1, D); x1 ^= x0;
  TF_R4(13,15,26,6)  x0 += ks1; x1 += ks2 + 1u;
  TF_R4(17,29,16,24) x0 += ks2; x1 += ks0 + 2u;
  TF_R4(13,15,26,6)  x0 += ks0; x1 += ks1 + 3u;
  TF_R4(17,29,16,24) x0 += ks1; x1 += ks2 + 4u;
  TF_R4(13,15,26,6)  x0 += ks2; x1 += ks0 + 5u;
#undef TF_R4
  U2 r; r.a = x0; r.b = x1; return r;
}

// partitionable 32-bit draw: bits1 ^ bits2  (VERIFIED passing, round 4)
__device__ __forceinline__ float jax_uniform(unsigned idx) {
  U2 r = threefry(0u, idx);
  unsigned bits = r.a ^ r.b;
  unsigned fb = (bits >> 9) | 0x3f800000u;
  return __uint_as_float(fb) - 1.0f;
}

// ============ f64-MFMA D-fragment layout probe (VERIFIED round 7) ==========
__global__ __launch_bounds__(64) void probe_layout(unsigned* __restrict__ maps) {
  __shared__ double X1[16][5], X2[16][5], W1s[4][17], W2s[4][17];
  const int l = threadIdx.x;
  const int lr = l & 15, lk = l >> 4;
  {
    int i = l >> 2, k = l & 3;
    X1[i][k] = (k == 0) ? (double)i : 0.0;   // D1[i][j] = i
    X2[i][k] = (k == 0) ? 1.0 : 0.0;         // D2[i][j] = j
    W1s[k][i] = (k == 0) ? 1.0 : 0.0;
    W2s[k][i] = (k == 0) ? (double)i : 0.0;
  }
  __syncthreads();
  f64x4 a1 = {0.0, 0.0, 0.0, 0.0}, a2 = {0.0, 0.0, 0.0, 0.0};
  a1 = __builtin_amdgcn_mfma_f64_16x16x4f64(X1[lr][lk], W1s[lk][lr], a1, 0, 0, 0);
  a2 = __builtin_amdgcn_mfma_f64_16x16x4f64(X2[lr][lk], W2s[lk][lr], a2, 0, 0, 0);
  unsigned m = 0;
  #pragma unroll
  for (int r = 0; r < 4; ++r) {
    int row = (int)(a1[r] + 0.5);
    int col = (int)(a2[r] + 0.5);
    m |= (unsigned)(((row & 15) << 4) | (col & 15)) << (8 * r);
  }
  maps[l] = m;
}

// ======================= FAST PATH: f64-MFMA GEMM (A-direct, W-dbuf) =======
template<int M, int N, int MODE>
__global__ __launch_bounds__(256, 3) void gemm_mfma(
    const void* __restrict__ inv, const float* __restrict__ W,
    const float* __restrict__ bias,
    const double* __restrict__ bna, const double* __restrict__ bnc,
    const unsigned* __restrict__ maps_g,
    double* __restrict__ hout, double* __restrict__ partials)
{
  constexpr int BK = 16;
  constexpr int NT = (N + 15) / 16;
  constexpr int NPAD = NT * 16;
  constexpr int WSTR = NPAD + 2;              // lk-groups 8 banks apart
  constexpr int NCH = (M + BK - 1) / BK;
  constexpr int NW = BK * NPAD;
  constexpr int WLD = (NW + 255) / 256;
  constexpr int SMK = (MODE == 1) ? (NCH * BK) : 1;

  struct SMM { float ws[2][BK][WSTR]; double bn[2][SMK]; };
  union SMEM { SMM m; double tt[4][16][17]; };
  __shared__ SMEM sm;

  const int tid = threadIdx.x;
  const int w = tid >> 6, l = tid & 63;
  const int lr = l & 15, lk = l >> 4;
  const long i0 = (long)blockIdx.x * 64;
  const int wrow = w * 16;
  const unsigned um = maps_g[l];
  const long arow = i0 + wrow + lr;           // this lane's A row

  if constexpr (MODE == 1) {
    for (int k = tid; k < SMK; k += 256) {
      sm.m.bn[0][k] = (k < M) ? bna[k] : 0.0;
      sm.m.bn[1][k] = (k < M) ? bnc[k] : 0.0;
    }
  }

  float wreg[WLD];
  float a4f[4], a4fn[4];
  double a4d[4], a4dn[4];

  auto loadW = [&](int k0) {
    #pragma unroll
    for (int p = 0; p < WLD; ++p) {
      int idx = tid + p * 256;
      float v = 0.0f;
      if (idx < NW) {
        int j = idx >> 4, kk = idx & 15;
        int k = k0 + kk;
        if (j < N && k < M) v = W[(long)j * M + k];
      }
      wreg[p] = v;
    }
  };
  auto writeW = [&](int buf) {
    #pragma unroll
    for (int p = 0; p < WLD; ++p) {
      int idx = tid + p * 256;
      if (idx < NW) {
        int j = idx >> 4, kk = idx & 15;
        sm.m.ws[buf][kk][j] = wreg[p];
      }
    }
  };
  auto loadA = [&](int k0, bool nxt) {
    int kb = k0 + lk * 4;
    if constexpr (MODE == 0) {
      float* dst = nxt ? a4fn : a4f;
      if (kb + 4 <= M) {
        float4 v = *(const float4*)((const float*)inv + arow * (long)M + kb);
        dst[0] = v.x; dst[1] = v.y; dst[2] = v.z; dst[3] = v.w;
      } else {
        #pragma unroll
        for (int e = 0; e < 4; ++e)
          dst[e] = (kb + e < M) ? ((const float*)inv)[arow * (long)M + kb + e] : 0.0f;
      }
    } else {
      double* dst = nxt ? a4dn : a4d;
      #pragma unroll
      for (int e = 0; e < 4; ++e)
        dst[e] = (kb + e < M) ? ((const double*)inv)[arow * (long)M + kb + e] : 0.0;
    }
  };

  f64x4 acc[NT];
  #pragma unroll
  for (int t = 0; t < NT; ++t) acc[t] = (f64x4){0.0, 0.0, 0.0, 0.0};

  loadA(0, false);
  loadW(0);
  writeW(0);
  __syncthreads();
  int cur = 0;
  for (int ch = 0; ch < NCH; ++ch) {
    const int k0 = ch * BK;
    if (ch + 1 < NCH) { loadA(k0 + BK, true); loadW(k0 + BK); }
    #pragma unroll
    for (int ks = 0; ks < 4; ++ks) {
      double aA;
      if constexpr (MODE == 0) {
        aA = (double)a4f[ks];
      } else {
        int k = k0 + lk * 4 + ks;
        double v = a4d[ks] * sm.m.bn[0][k] + sm.m.bn[1][k];
        aA = v > 0.0 ? v : 0.0;
      }
      #pragma unroll
      for (int t = 0; t < NT; ++t) {
        double bB = (double)sm.m.ws[cur][lk * 4 + ks][t * 16 + lr];
        acc[t] = __builtin_amdgcn_mfma_f64_16x16x4f64(aA, bB, acc[t], 0, 0, 0);
      }
    }
    if (ch + 1 < NCH) writeW(cur ^ 1);
    __syncthreads();
    if (ch + 1 < NCH) {
      if constexpr (MODE == 0) {
        #pragma unroll
        for (int e = 0; e < 4; ++e) a4f[e] = a4fn[e];
      } else {
        #pragma unroll
        for (int e = 0; e < 4; ++e) a4d[e] = a4dn[e];
      }
      cur ^= 1;
    }
  }

  // ---- epilogue: map-driven LDS transpose (tt unions staging), store+stats --
  const int blk = blockIdx.x;
  for (int t = 0; t < NT; ++t) {
    __syncthreads();
    #pragma unroll
    for (int r = 0; r < 4; ++r) {
      unsigned b = (um >> (8 * r)) & 0xffu;
      sm.tt[w][b >> 4][b & 15] = acc[t][r];
    }
    __syncthreads();
    for (int idx = tid; idx < 1024; idx += 256) {
      int rb = idx >> 4, j16 = idx & 15;
      int j = t * 16 + j16;
      if (j < N) {
        double h = sm.tt[rb >> 4][rb & 15][j16] + (double)bias[j];
        hout[(i0 + rb) * (long)N + j] = h;
      }
    }
    if (tid < 64) {
      int j16 = tid >> 2, part = tid & 3;
      int j = t * 16 + j16;
      double s = 0.0, q = 0.0;
      if (j < N) {
        double bj = (double)bias[j];
        #pragma unroll
        for (int rr = 0; rr < 16; ++rr) {
          int rb = part * 16 + rr;
          double h = sm.tt[rb >> 4][rb & 15][j16] + bj;
          s += h; q += h * h;
        }
      }
      s += __shfl_xor(s, 1); s += __shfl_xor(s, 2);
      q += __shfl_xor(q, 1); q += __shfl_xor(q, 2);
      if (part == 0 && j < N) {
        partials[(long)j * GBLOCKS + blk] = s;
        partials[(long)(N + j) * GBLOCKS + blk] = q;
      }
    }
  }
}

// final: BN+ReLU(h4) -> Linear(50->64) -> sigmoid -> sample -> logsum
__global__ __launch_bounds__(256) void final_store(
    const double* __restrict__ h4,
    const double* __restrict__ bna, const double* __restrict__ bnc,
    const float* __restrict__ W5, const float* __restrict__ b5,
    float* __restrict__ out0, float* __restrict__ out1)
{
  __shared__ double A5[ROWS][51];
  __shared__ double W5S[50][65];
  __shared__ double T[ROWS][65];
  const int tid = threadIdx.x;
  const int c = tid & 63, g = tid >> 6;
  const long i0 = (long)blockIdx.x * ROWS;

  for (int idx = tid; idx < ROWS * 50; idx += 256) {
    int r = idx / 50, k = idx % 50;
    double v = h4[(i0 + r) * 50 + k] * bna[k] + bnc[k];
    A5[r][k] = v > 0.0 ? v : 0.0;
  }
  for (int idx = tid; idx < 64 * 50; idx += 256) {
    int j = idx / 50, k = idx % 50;
    W5S[k][j] = (double)W5[j * 50 + k];
  }
  __syncthreads();

  double acc[8];
  #pragma unroll
  for (int rr = 0; rr < 8; ++rr) acc[rr] = 0.0;
  for (int k = 0; k < 50; ++k) {
    double w = W5S[k][c];
    #pragma unroll
    for (int rr = 0; rr < 8; ++rr) acc[rr] += A5[g * 8 + rr][k] * w;
  }
  double bj = (double)b5[c];
  #pragma unroll
  for (int rr = 0; rr < 8; ++rr) {
    int r = g * 8 + rr;
    double h = acc[rr] + bj;
    double p = 1.0 / (1.0 + exp(-h));
    float uf = jax_uniform((unsigned)((i0 + r) * 64 + c));
    bool ch = ((double)uf < 1.0 - p);
    out0[(i0 + r) * 64 + c] = ch ? 0.0f : 1.0f;
    T[r][c] = log(ch ? (1.0 - p) : p);
  }
  __syncthreads();
  for (int r = tid; r < ROWS; r += 256) {
    double s = 0.0;
    for (int j = 0; j < 64; ++j) s += T[r][j];
    out1[i0 + r] = (float)s;
  }
}

// ======================= FALLBACK: recompute chain (verified) ==============
template<int M, int N>
__device__ __forceinline__ void step_gemm(const double* IN, const float* __restrict__ W,
                                          int tid, double* acc) {
  if (tid < N) {
    #pragma unroll
    for (int r = 0; r < 32; ++r) acc[r] = 0.0;
    for (int k = 0; k < M; ++k) {
      double wv = (double)W[tid * M + k];
      #pragma unroll
      for (int r = 0; r < 32; ++r) acc[r] += IN[r * M + k] * wv;
    }
  }
}

template<int N>
__device__ __forceinline__ void step_write(double* OUT, const double* acc,
                                           const float* __restrict__ b, int tid) {
  if (tid < N) {
    double bj = (double)b[tid];
    #pragma unroll
    for (int r = 0; r < 32; ++r) OUT[r * N + tid] = acc[r] + bj;
  }
}

// transposed partials layout: partials[j*NBLOCKS + blk]
template<int N>
__device__ __forceinline__ void step_stats(const double* acc, const float* __restrict__ b,
                                           double* partials, int blk, int tid) {
  if (tid < N) {
    double bj = (double)b[tid], s = 0.0, q = 0.0;
    #pragma unroll
    for (int r = 0; r < 32; ++r) { double h = acc[r] + bj; s += h; q += h * h; }
    partials[(long)tid * NBLOCKS + blk] = s;
    partials[(long)(N + tid) * NBLOCKS + blk] = q;
  }
}

template<int N>
__device__ __forceinline__ void apply_bn(double* BUF, const double* __restrict__ a,
                                         const double* __restrict__ c, int tid) {
  for (int idx = tid; idx < 32 * N; idx += 256) {
    int col = idx % N;
    double v = BUF[idx] * a[col] + c[col];
    BUF[idx] = v > 0.0 ? v : 0.0;
  }
}

template<int PL>
__global__ __launch_bounds__(256) void chain_pass(
    const float* __restrict__ ev,
    const float* __restrict__ W0, const float* __restrict__ b0,
    const float* __restrict__ W1, const float* __restrict__ b1,
    const float* __restrict__ W2, const float* __restrict__ b2,
    const float* __restrict__ W3, const float* __restrict__ b3,
    const float* __restrict__ W4, const float* __restrict__ b4,
    const float* __restrict__ W5, const float* __restrict__ b5,
    const double* __restrict__ bn_a, const double* __restrict__ bn_c,
    double* __restrict__ partials,
    float* __restrict__ out0, float* __restrict__ out1)
{
  __shared__ double SA[32 * 130];
  __shared__ double SB[32 * 110];
  const int tid = threadIdx.x;
  const int blk = blockIdx.x;
  const long i0 = (long)blk * 32;
  double acc[32];

  {
    float* evf = (float*)SA;
    if (tid < 130) {
      #pragma unroll
      for (int r = 0; r < 32; ++r) acc[r] = 0.0;
    }
    for (int c = 0; c < 4; ++c) {
      __syncthreads();
      for (int idx = tid; idx < 32 * 256; idx += 256) {
        int r = idx >> 8, kk = idx & 255;
        evf[idx] = ev[(i0 + r) * 1024 + c * 256 + kk];
      }
      __syncthreads();
      if (tid < 130) {
        for (int kk = 0; kk < 256; ++kk) {
          double wv = (double)W0[tid * 1024 + c * 256 + kk];
          #pragma unroll
          for (int r = 0; r < 32; ++r) acc[r] += (double)evf[r * 256 + kk] * wv;
        }
      }
    }
    __syncthreads();
    if constexpr (PL == 0) { step_stats<130>(acc, b0, partials, blk, tid); return; }
    step_write<130>(SA, acc, b0, tid);
    __syncthreads();
    apply_bn<130>(SA, bn_a + 0, bn_c + 0, tid);
    __syncthreads();
  }
  if constexpr (PL >= 1) {
    step_gemm<130, 110>(SA, W1, tid, acc);
    if constexpr (PL == 1) { step_stats<110>(acc, b1, partials, blk, tid); return; }
    __syncthreads();
    step_write<110>(SB, acc, b1, tid);
    __syncthreads();
    apply_bn<110>(SB, bn_a + 130, bn_c + 130, tid);
    __syncthreads();
  }
  if constexpr (PL >= 2) {
    step_gemm<110, 90>(SB, W2, tid, acc);
    if constexpr (PL == 2) { step_stats<90>(acc, b2, partials, blk, tid); return; }
    __syncthreads();
    step_write<90>(SA, acc, b2, tid);
    __syncthreads();
    apply_bn<90>(SA, bn_a + 240, bn_c + 240, tid);
    __syncthreads();
  }
  if constexpr (PL >= 3) {
    step_gemm<90, 70>(SA, W3, tid, acc);
    if constexpr (PL == 3) { step_stats<70>(acc, b3, partials, blk, tid); return; }
    __syncthreads();
    step_write<70>(SB, acc, b3, tid);
    __syncthreads();
    apply_bn<70>(SB, bn_a + 330, bn_c + 330, tid);
    __syncthreads();
  }
  if constexpr (PL >= 4) {
    step_gemm<70, 50>(SB, W4, tid, acc);
    if constexpr (PL == 4) { step_stats<50>(acc, b4, partials, blk, tid); return; }
    __syncthreads();
    step_write<50>(SA, acc, b4, tid);
    __syncthreads();
    apply_bn<50>(SA, bn_a + 400, bn_c + 400, tid);
    __syncthreads();
  }
  if constexpr (PL == 5) {
    if (tid < 64) {
      #pragma unroll
      for (int r = 0; r < 32; ++r) acc[r] = 0.0;
      for (int k = 0; k < 50; ++k) {
        double wv = (double)W5[tid * 50 + k];
        #pragma unroll
        for (int r = 0; r < 32; ++r) acc[r] += SA[r * 50 + k] * wv;
      }
      double bj = (double)b5[tid];
      #pragma unroll
      for (int r = 0; r < 32; ++r) {
        double h = acc[r] + bj;
        double p = 1.0 / (1.0 + exp(-h));
        float uf = jax_uniform((unsigned)((i0 + r) * 64 + tid));
        bool ch = ((double)uf < 1.0 - p);
        out0[(i0 + r) * 64 + tid] = ch ? 0.0f : 1.0f;
        double d = ch ? (1.0 - p) : p;
        SB[r * 64 + tid] = log(d);
      }
    }
    __syncthreads();
    if (tid < 32) {
      double s = 0.0;
      for (int j = 0; j < 64; ++j) s += SB[tid * 64 + j];
      out1[i0 + tid] = (float)s;
    }
  }
}

// ------- BN stats finalize: transposed partials -> a, c (coalesced) --------
template<int N>
__global__ __launch_bounds__(256) void bn_finalize2(
    const double* __restrict__ partials, int nblocks,
    const float* __restrict__ g, const float* __restrict__ be,
    double* __restrict__ a, double* __restrict__ c)
{
  const int j = blockIdx.x;
  const int tid = threadIdx.x;
  double s = 0.0, q = 0.0;
  for (int b = tid; b < nblocks; b += 256) {
    s += partials[(long)j * nblocks + b];
    q += partials[(long)(N + j) * nblocks + b];
  }
  __shared__ double ls[256], lq[256];
  ls[tid] = s; lq[tid] = q;
  __syncthreads();
  for (int off = 128; off > 0; off >>= 1) {
    if (tid < off) { ls[tid] += ls[tid + off]; lq[tid] += lq[tid + off]; }
    __syncthreads();
  }
  if (tid == 0) {
    double mu  = ls[0] * (1.0 / 131072.0);
    double var = lq[0] * (1.0 / 131072.0) - mu * mu;
    double aj  = (double)g[j] / sqrt(var + 1e-5);
    a[j] = aj;
    c[j] = (double)be[j] - mu * aj;
  }
}

// ---------------- host side ----------------
extern "C" void kernel_launch(void* const* d_in, const int* in_sizes, int n_in,
                              void* d_out, int out_size, void* d_ws, size_t ws_size,
                              hipStream_t stream)
{
  const float* F[23];
  for (int i = 0; i < 23; ++i) F[i] = (const float*)d_in[i];
  const float* ev = F[0];
  float* out0 = (float*)d_out;
  float* out1 = out0 + BATCH * 64;

  // partials live in d_out (consumed before the final pass overwrites it)
  double* partials = (double*)d_out;
  double* bn_a = (double*)d_ws;          // 450 doubles
  double* bn_c = bn_a + 450;             // 450 doubles
  unsigned* maps = (unsigned*)(bn_c + 450);  // 64 u32

  char* ws = (char*)d_ws;
  size_t used = (size_t)((char*)(maps + 64) - ws);
  used = (used + 255) & ~(size_t)255;
  const size_t needA = (size_t)BATCH * 130 * 8;   // 136.3 MB
  const size_t needB = (size_t)BATCH * 110 * 8;   // 115.3 MB

  dim3 b(256);

  if (ws_size >= used + needA + needB) {
    // ---------- fast stored-h path (f64 MFMA, probe-measured layout) ----------
    double* bufA = (double*)(ws + used);
    double* bufB = (double*)(ws + used + needA);
    dim3 g(GBLOCKS);
    probe_layout<<<dim3(1), dim3(64), 0, stream>>>(maps);
    gemm_mfma<1024, 130, 0><<<g, b, 0, stream>>>(ev, F[1], F[2],
        nullptr, nullptr, maps, bufA, partials);
    bn_finalize2<130><<<dim3(130), b, 0, stream>>>(partials, GBLOCKS, F[3], F[4], bn_a + 0, bn_c + 0);
    gemm_mfma<130, 110, 1><<<g, b, 0, stream>>>(bufA, F[5], F[6],
        bn_a + 0, bn_c + 0, maps, bufB, partials);
    bn_finalize2<110><<<dim3(110), b, 0, stream>>>(partials, GBLOCKS, F[7], F[8], bn_a + 130, bn_c + 130);
    gemm_mfma<110, 90, 1><<<g, b, 0, stream>>>(bufB, F[9], F[10],
        bn_a + 130, bn_c + 130, maps, bufA, partials);
    bn_finalize2<90><<<dim3(90), b, 0, stream>>>(partials, GBLOCKS, F[11], F[12], bn_a + 240, bn_c + 240);
    gemm_mfma<90, 70, 1><<<g, b, 0, stream>>>(bufA, F[13], F[14],
        bn_a + 240, bn_c + 240, maps, bufB, partials);
    bn_finalize2<70><<<dim3(70), b, 0, stream>>>(partials, GBLOCKS, F[15], F[16], bn_a + 330, bn_c + 330);
    gemm_mfma<70, 50, 1><<<g, b, 0, stream>>>(bufB, F[17], F[18],
        bn_a + 330, bn_c + 330, maps, bufA, partials);
    bn_finalize2<50><<<dim3(50), b, 0, stream>>>(partials, GBLOCKS, F[19], F[20], bn_a + 400, bn_c + 400);
    final_store<<<dim3(NBLOCKS), b, 0, stream>>>(bufA, bn_a + 400, bn_c + 400, F[21], F[22], out0, out1);
  } else {
    // ---------- fallback: verified recompute chain ----------
    dim3 g(NBLOCKS);
#define ARGS ev, F[1],F[2], F[5],F[6], F[9],F[10], F[13],F[14], F[17],F[18], \
             F[21],F[22], bn_a, bn_c, partials, out0, out1
    chain_pass<0><<<g, b, 0, stream>>>(ARGS);
    bn_finalize2<130><<<dim3(130), b, 0, stream>>>(partials, NBLOCKS, F[3],  F[4],  bn_a + 0,   bn_c + 0);
    chain_pass<1><<<g, b, 0, stream>>>(ARGS);
    bn_finalize2<110><<<dim3(110), b, 0, stream>>>(partials, NBLOCKS, F[7],  F[8],  bn_a + 130, bn_c + 130);
    chain_pass<2><<<g, b, 0, stream>>>(ARGS);
    bn_finalize2<90><<<dim3(90),  b, 0, stream>>>(partials, NBLOCKS, F[11], F[12], bn_a + 240, bn_c + 240);
    chain_pass<3><<<g, b, 0, stream>>>(ARGS);
    bn_finalize2<70><<<dim3(70),  b, 0, stream>>>(partials, NBLOCKS, F[15], F[16], bn_a + 330, bn_c + 330);
    chain_pass<4><<<g, b, 0, stream>>>(ARGS);
    bn_finalize2<50><<<dim3(50),  b, 0, stream>>>(partials, NBLOCKS, F[19], F[20], bn_a + 400, bn_c + 400);
    chain_pass<5><<<g, b, 0, stream>>>(ARGS);
#undef ARGS
  }
}